// Round 3
// baseline (301.009 us; speedup 1.0000x reference)
//
#include <hip/hip_runtime.h>
#include <cstdint>
#include <cstddef>

// NonLocalBlock3D: B=2, C=256, Ci=128, N=D*H*W=8192.
// k0 prep -> k1 projections -> k2 flash attention (KV-split, 32x32 swapped MFMA)
// -> k2b combine -> k3 wy GEMM+stats -> k4 BN+residual.
// Softmax runs in exp2 domain (log2e folded into Wt/bt at pack time).

typedef unsigned short u16;
typedef __bf16 bf16x8 __attribute__((ext_vector_type(8)));
typedef float f32x4 __attribute__((ext_vector_type(4)));
typedef float f32x16 __attribute__((ext_vector_type(16)));
typedef unsigned short u16x8 __attribute__((ext_vector_type(8)));

#define B_ 2
#define C_ 256
#define CI_ 128
#define N_ 8192
#define KVB 64

static __device__ __forceinline__ u16 f2bf(float f){
  unsigned u = __builtin_bit_cast(unsigned, f);
  unsigned r = (u + 0x7FFFu + ((u>>16)&1u)) >> 16;
  return (u16)r;
}
static __device__ __forceinline__ float bf2f(u16 v){
  unsigned u = ((unsigned)v) << 16;
  return __builtin_bit_cast(float, u);
}
static __device__ __forceinline__ f32x4 f4zero(){
  f32x4 v; v[0]=0.f; v[1]=0.f; v[2]=0.f; v[3]=0.f; return v;
}
static __device__ __forceinline__ f32x16 f16zero(){
  f32x16 v;
#pragma unroll
  for (int i=0;i<16;i++) v[i]=0.f;
  return v;
}
static __device__ __forceinline__ f32x4 mfma16(bf16x8 a, bf16x8 b, f32x4 c){
  return __builtin_amdgcn_mfma_f32_16x16x32_bf16(a, b, c, 0, 0, 0);
}
static __device__ __forceinline__ f32x16 mfma32(bf16x8 a, bf16x8 b, f32x16 c){
  return __builtin_amdgcn_mfma_f32_32x32x16_bf16(a, b, c, 0, 0, 0);
}
static __device__ __forceinline__ unsigned cvtpk(float lo, float hi){
  unsigned r;
  asm("v_cvt_pk_bf16_f32 %0, %1, %2" : "=v"(r) : "v"(lo), "v"(hi));
  return r;
}
static __device__ __forceinline__ void plswap(unsigned &a, unsigned &b){
  asm volatile("v_permlane32_swap_b32 %0, %1" : "+v"(a), "+v"(b));
}

#define LOG2E 1.4426950408889634f

// ---------------- K0: weight pack (fp32 -> bf16), bias concat, zero stats ----------------
// Wt/bt pre-scaled by log2(e) so attention logits are already in log2 domain.
__global__ void k0_prep(const float* __restrict__ Wt, const float* __restrict__ Wp,
                        const float* __restrict__ Wg, const float* __restrict__ Ww,
                        const float* __restrict__ bt, const float* __restrict__ bp,
                        const float* __restrict__ bg,
                        u16* __restrict__ Wcat, u16* __restrict__ Wwb,
                        float* __restrict__ biasc, float* __restrict__ stats){
  int t = blockIdx.x*blockDim.x + threadIdx.x;
  int nthr = gridDim.x*blockDim.x;
  for (int i = t; i < 32768; i += nthr){
    Wcat[i]        = f2bf(Wt[i] * LOG2E);
    Wcat[32768+i]  = f2bf(Wp[i]);
    Wcat[65536+i]  = f2bf(Wg[i]);
    Wwb[i]         = f2bf(Ww[i]);
  }
  for (int i = t; i < 128; i += nthr){
    biasc[i] = bt[i] * LOG2E; biasc[128+i] = bp[i]; biasc[256+i] = bg[i];
  }
  for (int i = t; i < 512; i += nthr) stats[i] = 0.f;
}

// ---------------- K1: fused transpose + 3 projections ----------------
__global__ __launch_bounds__(256) void k1_proj(const float* __restrict__ x,
     const u16* __restrict__ Wcat, const float* __restrict__ biasc,
     u16* __restrict__ theta, u16* __restrict__ kproj, u16* __restrict__ gT){
  __shared__ u16 At[64*264];
  __shared__ u16 Wt_[32*264];
  __shared__ u16 gbuf[32*72];
  int tid = threadIdx.x;
  int b  = blockIdx.x >> 7;
  int nb = (blockIdx.x & 127) * 64;
  int w = tid >> 6, lane = tid & 63;
  int l15 = lane & 15, kg = lane >> 4;

  {
    int cp = tid & 127, nh = tid >> 7;
    int c0 = cp*2;
    const float* src0 = x + ((size_t)(b*C_ + c0))*N_ + nb + nh*32;
    const float* src1 = src0 + N_;
#pragma unroll
    for (int j=0;j<8;j++){
      f32x4 a = *(const f32x4*)(src0 + j*4);
      f32x4 c = *(const f32x4*)(src1 + j*4);
#pragma unroll
      for (int q=0;q<4;q++){
        unsigned pk = (unsigned)f2bf(a[q]) | ((unsigned)f2bf(c[q])<<16);
        *(unsigned*)&At[(nh*32 + j*4 + q)*264 + c0] = pk;
      }
    }
  }
  __syncthreads();

  bf16x8 afr[8];
#pragma unroll
  for (int kc=0;kc<8;kc++)
    afr[kc] = *(const bf16x8*)&At[(w*16+l15)*264 + kc*32 + kg*8];

  for (int och = 0; och < 12; och++){
    {
      int o8 = tid>>3, cp8 = tid&7;
      const u16* wsrc = Wcat + ((size_t)(och*32 + o8))*256 + cp8*8;
#pragma unroll
      for (int j=0;j<4;j++)
        *(u16x8*)&Wt_[o8*264 + cp8*8 + j*64] = *(const u16x8*)(wsrc + j*64);
    }
    __syncthreads();

    f32x4 acc0 = f4zero(), acc1 = f4zero();
#pragma unroll
    for (int kc=0;kc<8;kc++){
      bf16x8 b0 = *(const bf16x8*)&Wt_[(l15)*264 + kc*32 + kg*8];
      bf16x8 b1 = *(const bf16x8*)&Wt_[(16+l15)*264 + kc*32 + kg*8];
      acc0 = mfma16(afr[kc], b0, acc0);
      acc1 = mfma16(afr[kc], b1, acc1);
    }

    if (och < 8){
      u16* dst = (och < 4) ? theta : kproj;
      int oo = (och & 3) * 32;
#pragma unroll
      for (int of=0;of<2;of++){
        int o = oo + of*16 + l15;
        float bias = biasc[och*32 + of*16 + l15];
        f32x4 acc = of ? acc1 : acc0;
#pragma unroll
        for (int i=0;i<4;i++){
          int n = nb + w*16 + kg*4 + i;
          dst[((size_t)b*N_ + n)*CI_ + o] = f2bf(acc[i] + bias);
        }
      }
      __syncthreads();
    } else {
#pragma unroll
      for (int of=0;of<2;of++){
        int o = of*16 + l15;
        float bias = biasc[och*32 + of*16 + l15];
        f32x4 acc = of ? acc1 : acc0;
#pragma unroll
        for (int i=0;i<4;i++){
          int r = w*16 + kg*4 + i;
          gbuf[o*72 + r] = f2bf(acc[i] + bias);
        }
      }
      __syncthreads();
      {
        int o = tid>>3, np = tid&7;
        int og = (och-8)*32 + o;
        u16x8 v = *(const u16x8*)&gbuf[o*72 + np*8];
        *(u16x8*)(gT + ((size_t)b*CI_ + og)*N_ + nb + np*8) = v;
      }
      __syncthreads();
    }
  }
}

// ---------------- K2: flash attention, swapped 32x32 MFMA, KV-split ----------------
// Grid 64*CH blocks x 512 threads (8 waves x 32 q-rows). bid&(2CH-1) = (b,chunk).
// Kt [64 k][128 c] bf16 XOR-swizzled; Vt [128 c][64 k] bf16 XOR-swizzled; dbuf; 64 KB LDS.
template<int CH>
__global__ __launch_bounds__(512, 4) void k2_attn(const u16* __restrict__ theta,
      const u16* __restrict__ kproj, const u16* __restrict__ gT,
      u16* __restrict__ pO, float* __restrict__ pM, float* __restrict__ pL){
  constexpr int CHUNK_N = N_ / CH;
  constexpr int NTI = CHUNK_N / KVB;
  __shared__ char smem[65536];   // [0,32K): Kt dbuf, [32K,64K): Vt dbuf
  char* kbase = smem;
  char* vbase = smem + 32768;
  int tid = threadIdx.x;
  int bid = blockIdx.x;
  int combo = bid & (2*CH - 1);
  int b = combo & 1;
  int chunk = combo >> 1;
  int qblk = bid / (2*CH);             // 0..31
  int n0 = chunk * CHUNK_N;
  int w = tid >> 6, lane = tid & 63;
  int l31 = lane & 31, hi = lane >> 5;
  int qg = qblk*256 + w*32 + l31;

  // Q into registers: lane holds its hi-half of row qg (64 of 128 channels)
  bf16x8 qf[8];
  {
    const u16* qsrc = theta + ((size_t)b*N_ + qg)*CI_ + hi*8;
#pragma unroll
    for (int cc=0; cc<8; cc++) qf[cc] = *(const bf16x8*)(qsrc + cc*16);
  }

  // staging assignment (512 threads, 32 B each per tile per array)
  int krow_s = tid >> 3, kpart = tid & 7;
  int vrow_s = tid >> 2, vpart = tid & 3;
  const u16* ksrc = kproj + ((size_t)b*N_ + n0 + krow_s)*CI_ + kpart*16;
  const u16* vsrc = gT + ((size_t)b*CI_ + vrow_s)*N_ + n0 + vpart*16;
  int kw_off[2], vw_off[2];
#pragma unroll
  for (int j=0;j<2;j++){
    int cb = kpart*32 + j*16;
    kw_off[j] = krow_s*256 + (cb ^ ((krow_s&7)<<4));
    int kb = vpart*32 + j*16;
    vw_off[j] = vrow_s*128 + (kb ^ ((vrow_s&7)<<4));
  }
  // precomputed read offsets (within one buffer)
  int swz = (l31&7)<<4;
  int kro[8], vro[4];
#pragma unroll
  for (int cc=0;cc<8;cc++) kro[cc] = l31*256 + ((cc*32 + hi*16) ^ swz);
#pragma unroll
  for (int ks=0;ks<4;ks++) vro[ks] = l31*128 + ((ks*32 + hi*16) ^ swz);

  // prologue: stage tile 0 into buf0
#pragma unroll
  for (int j=0;j<2;j++){
    *(u16x8*)(kbase + kw_off[j]) = *(const u16x8*)(ksrc + j*8);
    *(u16x8*)(vbase + vw_off[j]) = *(const u16x8*)(vsrc + j*8);
  }
  __syncthreads();

  f32x16 oacc[4];
#pragma unroll
  for (int i=0;i<4;i++) oacc[i] = f16zero();
  float mrun = -1e30f, lrun = 0.f;

  for (int t=0; t<NTI; t++){
    int cur = t & 1;
    char* kb_c = kbase + cur*16384;
    char* vb_c = vbase + cur*16384;
    u16x8 kst[2], vst[2];
    bool pf = (t+1 < NTI);
    if (pf){
      const u16* ks = ksrc + (size_t)(t+1)*KVB*CI_;
      const u16* vs = vsrc + (t+1)*KVB;
#pragma unroll
      for (int j=0;j<2;j++) kst[j] = *(const u16x8*)(ks + j*8);
#pragma unroll
      for (int j=0;j<2;j++) vst[j] = *(const u16x8*)(vs + j*8);
    }

    // --- QK^T (swapped): sA = S^T rows k 0..31, sB rows k 32..63; col = q = l31
    f32x16 sA = f16zero(), sB = f16zero();
    __builtin_amdgcn_s_setprio(1);
#pragma unroll
    for (int cc=0; cc<8; cc++){
      bf16x8 kf0 = *(const bf16x8*)(kb_c + kro[cc]);
      bf16x8 kf1 = *(const bf16x8*)(kb_c + 8192 + kro[cc]);
      sA = mfma32(kf0, qf[cc], sA);
      sB = mfma32(kf1, qf[cc], sB);
    }
    __builtin_amdgcn_s_setprio(0);

    // --- online softmax (exp2 domain), fully in-register
    float t8[8];
#pragma unroll
    for (int i=0;i<8;i++) t8[i] = fmaxf(fmaxf(sA[i], sA[i+8]), fmaxf(sB[i], sB[i+8]));
    float m4a = fmaxf(t8[0], t8[4]), m4b = fmaxf(t8[1], t8[5]);
    float m4c = fmaxf(t8[2], t8[6]), m4d = fmaxf(t8[3], t8[7]);
    float mx = fmaxf(fmaxf(m4a, m4b), fmaxf(m4c, m4d));
    mx = fmaxf(mx, __shfl_xor(mx, 32));
    if (__any(mx > mrun + 12.f)){       // T13 defer-max (12 in log2 units)
      float mnew = fmaxf(mrun, mx);
      float sc = exp2f(mrun - mnew);
      lrun *= sc;
#pragma unroll
      for (int i=0;i<4;i++)
#pragma unroll
        for (int r=0;r<16;r++) oacc[i][r] *= sc;
      mrun = mnew;
    }
    float pA[16], pB[16];
#pragma unroll
    for (int r=0;r<16;r++){ pA[r] = exp2f(sA[r]-mrun); pB[r] = exp2f(sB[r]-mrun); }
    float s8[8];
#pragma unroll
    for (int i=0;i<8;i++) s8[i] = (pA[i]+pA[i+8]) + (pB[i]+pB[i+8]);
    float s4a = s8[0]+s8[4], s4b = s8[1]+s8[5], s4c = s8[2]+s8[6], s4d = s8[3]+s8[7];
    float ps = (s4a+s4b) + (s4c+s4d);
    ps += __shfl_xor(ps, 32);
    lrun += ps;

    // --- T14 write-late: staged regs -> other buffer (overlaps with PV)
    if (pf){
      char* kd = kbase + (cur^1)*16384;
      char* vd = vbase + (cur^1)*16384;
#pragma unroll
      for (int j=0;j<2;j++) *(u16x8*)(kd + kw_off[j]) = kst[j];
#pragma unroll
      for (int j=0;j<2;j++) *(u16x8*)(vd + vw_off[j]) = vst[j];
    }

    // --- PV (swapped): oacc[c2] = O^T chunk rows c, col q = l31
    __builtin_amdgcn_s_setprio(1);
#pragma unroll
    for (int ks=0; ks<4; ks++){
      const float* P = (ks<2) ? pA : pB;
      int r0 = (ks&1)*8;
      unsigned a0 = cvtpk(P[r0+0], P[r0+1]);
      unsigned b0 = cvtpk(P[r0+4], P[r0+5]);
      unsigned a1 = cvtpk(P[r0+2], P[r0+3]);
      unsigned b1 = cvtpk(P[r0+6], P[r0+7]);
      plswap(a0, b0); plswap(a1, b1);
      union { unsigned u[4]; bf16x8 v; } pb;
      pb.u[0]=a0; pb.u[1]=a1; pb.u[2]=b0; pb.u[3]=b1;
#pragma unroll
      for (int c2=0; c2<4; c2++){
        bf16x8 vf = *(const bf16x8*)(vb_c + c2*4096 + vro[ks]);
        oacc[c2] = mfma32(vf, pb.v, oacc[c2]);
      }
    }
    __builtin_amdgcn_s_setprio(0);
    __syncthreads();
  }

  // --- epilogue: O^T -> per-wave LDS region (bf16, swizzled) -> coalesced partial store
  char* region = smem + w*8192;   // 32 q x 128 c bf16 = 8 KB
#pragma unroll
  for (int c2=0;c2<4;c2++)
#pragma unroll
    for (int r=0;r<16;r++){
      int c = c2*32 + (r&3) + 8*(r>>2) + 4*hi;
      *(u16*)(region + l31*256 + ((c*2) ^ swz)) = f2bf(oacc[c2][r]);
    }
  __syncthreads();
  {
    int ql = lane >> 1, half = lane & 1;
    int qg2 = qblk*256 + w*32 + ql;
    u16* dst = pO + ((size_t)(chunk*2 + b)*N_ + qg2)*CI_ + half*64;
    int rswz = (ql&7)<<4;
#pragma unroll
    for (int j=0;j<8;j++){
      u16x8 v2 = *(const u16x8*)(region + ql*256 + ((half*128 + j*16) ^ rswz));
      *(u16x8*)(dst + j*8) = v2;
    }
  }
  if (hi == 0){
    pM[(size_t)(chunk*2 + b)*N_ + qg] = mrun;
    pL[(size_t)(chunk*2 + b)*N_ + qg] = lrun;
  }
}

// ---------------- K2b: combine KV-chunk partials -> y (f32) ----------------
template<int CH>
__global__ __launch_bounds__(256) void k2b_combine(const u16* __restrict__ pO,
    const float* __restrict__ pM, const float* __restrict__ pL,
    float* __restrict__ y){
  int tid = threadIdx.x;
  int blk = blockIdx.x;                // 1024 blocks: b * 512 + qgroup
  int b = blk >> 9;
  int q = (blk & 511) * 16 + (tid >> 4);
  int c0 = (tid & 15) * 8;
  size_t qi = (size_t)b*N_ + q;
  float m[CH], l[CH];
#pragma unroll
  for (int ch=0; ch<CH; ch++){
    m[ch] = pM[(size_t)(ch*2)*N_ + qi];
    l[ch] = pL[(size_t)(ch*2)*N_ + qi];
  }
  float M = m[0];
#pragma unroll
  for (int ch=1; ch<CH; ch++) M = fmaxf(M, m[ch]);
  float wts[CH];
  float L = 0.f;
#pragma unroll
  for (int ch=0; ch<CH; ch++){ wts[ch] = exp2f(m[ch]-M); L += wts[ch]*l[ch]; }
  float inv = 1.f/L;
  float acc[8];
#pragma unroll
  for (int i=0;i<8;i++) acc[i]=0.f;
  const u16* src = pO + qi*CI_ + c0;
#pragma unroll
  for (int ch=0; ch<CH; ch++){
    u16x8 v = *(const u16x8*)(src + (size_t)ch*2*N_*CI_);
#pragma unroll
    for (int i=0;i<8;i++) acc[i] += wts[ch]*bf2f(v[i]);
  }
  float* dst = y + qi*CI_ + c0;
  f32x4 o0, o1;
#pragma unroll
  for (int i=0;i<4;i++){ o0[i] = acc[i]*inv; o1[i] = acc[4+i]*inv; }
  *(f32x4*)dst = o0;
  *(f32x4*)(dst+4) = o1;
}

// ---------------- K3: wy = Ww @ y + bw, plus per-channel sum/sumsq ----------------
__global__ __launch_bounds__(256) void k3_wy(const float* __restrict__ y,
    const u16* __restrict__ Wwb, const float* __restrict__ bw,
    float* __restrict__ wy, float* __restrict__ stats){
  __shared__ u16 Yt[64*136];
  __shared__ u16 Wt_[64*136];
  __shared__ float wyb[64*72];
  int tid = threadIdx.x;
  int b  = blockIdx.x >> 7;
  int nb = (blockIdx.x & 127) * 64;
  int w = tid>>6, lane = tid&63;
  int l15 = lane&15, kg = lane>>4;

  {
    int n = tid>>2, cp = tid&3;
    const float* src = y + ((size_t)b*N_ + nb + n)*CI_ + cp*32;
#pragma unroll
    for (int j=0;j<8;j++){
      f32x4 v = *(const f32x4*)(src + j*4);
      unsigned p0 = (unsigned)f2bf(v[0]) | ((unsigned)f2bf(v[1])<<16);
      unsigned p1 = (unsigned)f2bf(v[2]) | ((unsigned)f2bf(v[3])<<16);
      *(unsigned*)&Yt[n*136 + cp*32 + j*4]     = p0;
      *(unsigned*)&Yt[n*136 + cp*32 + j*4 + 2] = p1;
    }
  }
  __syncthreads();

  bf16x8 afr[4];
#pragma unroll
  for (int kc=0;kc<4;kc++)
    afr[kc] = *(const bf16x8*)&Yt[(w*16+l15)*136 + kc*32 + kg*8];

  for (int oc=0; oc<4; oc++){
    {
      int o = tid>>2, cp = tid&3;
      const u16* src = Wwb + ((size_t)(oc*64 + o))*CI_ + cp*32;
#pragma unroll
      for (int j=0;j<4;j++)
        *(u16x8*)&Wt_[o*136 + cp*32 + j*8] = *(const u16x8*)(src + j*8);
    }
    __syncthreads();

    f32x4 acc[4];
#pragma unroll
    for (int of=0;of<4;of++) acc[of] = f4zero();
#pragma unroll
    for (int kc=0;kc<4;kc++){
#pragma unroll
      for (int of=0;of<4;of++){
        bf16x8 bfr = *(const bf16x8*)&Wt_[(of*16+l15)*136 + kc*32 + kg*8];
        acc[of] = mfma16(afr[kc], bfr, acc[of]);
      }
    }
#pragma unroll
    for (int of=0;of<4;of++){
#pragma unroll
      for (int i=0;i<4;i++)
        wyb[(of*16+l15)*72 + w*16 + kg*4 + i] = acc[of][i];
    }
    __syncthreads();
    {
      int o = tid>>2, np = tid&3;
      int og = oc*64 + o;
      float bias = bw[og];
      float sm = 0.f, sq = 0.f;
      float* dst = wy + ((size_t)b*C_ + og)*N_ + nb + np*16;
#pragma unroll
      for (int j=0;j<4;j++){
        f32x4 v;
#pragma unroll
        for (int q=0;q<4;q++){
          float t2 = wyb[o*72 + np*16 + j*4 + q] + bias;
          v[q] = t2; sm += t2; sq += t2*t2;
        }
        *(f32x4*)(dst + j*4) = v;
      }
      sm += __shfl_xor(sm, 1); sm += __shfl_xor(sm, 2);
      sq += __shfl_xor(sq, 1); sq += __shfl_xor(sq, 2);
      if ((tid&3)==0){
        atomicAdd(&stats[og], sm);
        atomicAdd(&stats[256+og], sq);
      }
    }
    __syncthreads();
  }
}

// ---------------- K4: BN (batch stats) + residual ----------------
__global__ __launch_bounds__(256) void k4_bn(const float* __restrict__ wy,
    const float* __restrict__ x, const float* __restrict__ stats,
    const float* __restrict__ gamma, const float* __restrict__ beta,
    float* __restrict__ out){
  size_t base = ((size_t)blockIdx.x)*2048 + (size_t)threadIdx.x*8;
  int o = (int)((base >> 13) & 255);
  const float invn = 1.f/16384.f;
  float mean = stats[o]*invn;
  float var  = stats[256+o]*invn - mean*mean;
  float rs = rsqrtf(var + 1e-5f);
  float g = gamma[o]*rs;
  float bb = beta[o];
  f32x4 a0 = *(const f32x4*)(wy + base);
  f32x4 a1 = *(const f32x4*)(wy + base + 4);
  f32x4 x0 = *(const f32x4*)(x + base);
  f32x4 x1 = *(const f32x4*)(x + base + 4);
  f32x4 r0, r1;
#pragma unroll
  for (int q=0;q<4;q++){
    r0[q] = (a0[q]-mean)*g + bb + x0[q];
    r1[q] = (a1[q]-mean)*g + bb + x1[q];
  }
  *(f32x4*)(out + base)     = r0;
  *(f32x4*)(out + base + 4) = r1;
}

extern "C" void kernel_launch(void* const* d_in, const int* in_sizes, int n_in,
                              void* d_out, int out_size, void* d_ws, size_t ws_size,
                              hipStream_t stream){
  const float* x     = (const float*)d_in[0];
  const float* Wt    = (const float*)d_in[1];
  const float* bt    = (const float*)d_in[2];
  const float* Wp    = (const float*)d_in[3];
  const float* bp    = (const float*)d_in[4];
  const float* Wg    = (const float*)d_in[5];
  const float* bg    = (const float*)d_in[6];
  const float* Ww    = (const float*)d_in[7];
  const float* bw    = (const float*)d_in[8];
  const float* gamma = (const float*)d_in[9];
  const float* beta  = (const float*)d_in[10];

  // big layout (CH=8) needs: 12M proj + 32M pO + 1M pM/pL + ~264K weights = ~47.5MB
  const size_t BIG_NEED = 47451648;
  bool big = (ws_size >= BIG_NEED);

  char* ws = (char*)d_ws;
  u16*   theta = (u16*)(ws + 0);
  u16*   kproj = (u16*)(ws + 4194304);
  u16*   gT    = (u16*)(ws + 8388608);
  u16*   pO    = (u16*)(ws + 12582912);
  size_t po_bytes = big ? (size_t)33554432 : (size_t)16777216;
  char*  tail  = ws + 12582912 + po_bytes;
  float* pM    = (float*)(tail);
  size_t ml_bytes = big ? (size_t)524288 : (size_t)262144;
  float* pL    = (float*)(tail + ml_bytes);
  u16*   Wcat  = (u16*)(tail + 2*ml_bytes);
  u16*   Wwb   = (u16*)(tail + 2*ml_bytes + 196608);
  float* biasc = (float*)(tail + 2*ml_bytes + 262144);
  float* stats = (float*)(tail + 2*ml_bytes + 263680);
  float* y     = (float*)(ws + 0);          // aliases theta+kproj (dead after k2)
  float* wy    = (float*)(ws + 12582912);   // aliases pO (dead after k2b)
  float* out   = (float*)d_out;

  k0_prep<<<64, 256, 0, stream>>>(Wt, Wp, Wg, Ww, bt, bp, bg, Wcat, Wwb, biasc, stats);
  k1_proj<<<256, 256, 0, stream>>>(x, Wcat, biasc, theta, kproj, gT);
  if (big){
    k2_attn<8><<<512, 512, 0, stream>>>(theta, kproj, gT, pO, pM, pL);
    k2b_combine<8><<<1024, 256, 0, stream>>>(pO, pM, pL, y);
  } else {
    k2_attn<4><<<256, 512, 0, stream>>>(theta, kproj, gT, pO, pM, pL);
    k2b_combine<4><<<1024, 256, 0, stream>>>(pO, pM, pL, y);
  }
  k3_wy<<<256, 256, 0, stream>>>(y, Wwb, bw, wy, stats);
  k4_bn<<<2048, 256, 0, stream>>>(wy, x, stats, gamma, beta, out);
}

// Round 4
// 162.970 us; speedup vs baseline: 1.8470x; 1.8470x over previous
//
#include <hip/hip_runtime.h>
#include <cstdint>
#include <cstddef>

// NonLocalBlock3D: B=2, C=256, Ci=128, N=D*H*W=8192.
// k0 prep -> k1 projections -> k2 flash attention (KV-split, 32x32 swapped MFMA)
// -> k2b combine -> k3 wy GEMM+stats -> k4 BN+residual.
// Softmax runs in exp2 domain (log2e folded into Wt/bt at pack time).
// NOTE: k2_attn must be __launch_bounds__(512,2): asking for 4 waves/EU caps
// VGPR at 64 and the kernel spills ~600 MB of scratch per launch (R3 post-mortem).

typedef unsigned short u16;
typedef __bf16 bf16x8 __attribute__((ext_vector_type(8)));
typedef float f32x4 __attribute__((ext_vector_type(4)));
typedef float f32x16 __attribute__((ext_vector_type(16)));
typedef unsigned short u16x8 __attribute__((ext_vector_type(8)));

#define B_ 2
#define C_ 256
#define CI_ 128
#define N_ 8192
#define KVB 64

static __device__ __forceinline__ u16 f2bf(float f){
  unsigned u = __builtin_bit_cast(unsigned, f);
  unsigned r = (u + 0x7FFFu + ((u>>16)&1u)) >> 16;
  return (u16)r;
}
static __device__ __forceinline__ float bf2f(u16 v){
  unsigned u = ((unsigned)v) << 16;
  return __builtin_bit_cast(float, u);
}
static __device__ __forceinline__ f32x4 f4zero(){
  f32x4 v; v[0]=0.f; v[1]=0.f; v[2]=0.f; v[3]=0.f; return v;
}
static __device__ __forceinline__ f32x16 f16zero(){
  f32x16 v;
#pragma unroll
  for (int i=0;i<16;i++) v[i]=0.f;
  return v;
}
static __device__ __forceinline__ f32x4 mfma16(bf16x8 a, bf16x8 b, f32x4 c){
  return __builtin_amdgcn_mfma_f32_16x16x32_bf16(a, b, c, 0, 0, 0);
}
static __device__ __forceinline__ f32x16 mfma32(bf16x8 a, bf16x8 b, f32x16 c){
  return __builtin_amdgcn_mfma_f32_32x32x16_bf16(a, b, c, 0, 0, 0);
}
static __device__ __forceinline__ unsigned cvtpk(float lo, float hi){
  unsigned r;
  asm("v_cvt_pk_bf16_f32 %0, %1, %2" : "=v"(r) : "v"(lo), "v"(hi));
  return r;
}
static __device__ __forceinline__ void plswap(unsigned &a, unsigned &b){
  asm volatile("v_permlane32_swap_b32 %0, %1" : "+v"(a), "+v"(b));
}

#define LOG2E 1.4426950408889634f

// ---------------- K0: weight pack (fp32 -> bf16), bias concat, zero stats ----------------
// Wt/bt pre-scaled by log2(e) so attention logits are already in log2 domain.
__global__ void k0_prep(const float* __restrict__ Wt, const float* __restrict__ Wp,
                        const float* __restrict__ Wg, const float* __restrict__ Ww,
                        const float* __restrict__ bt, const float* __restrict__ bp,
                        const float* __restrict__ bg,
                        u16* __restrict__ Wcat, u16* __restrict__ Wwb,
                        float* __restrict__ biasc, float* __restrict__ stats){
  int t = blockIdx.x*blockDim.x + threadIdx.x;
  int nthr = gridDim.x*blockDim.x;
  for (int i = t; i < 32768; i += nthr){
    Wcat[i]        = f2bf(Wt[i] * LOG2E);
    Wcat[32768+i]  = f2bf(Wp[i]);
    Wcat[65536+i]  = f2bf(Wg[i]);
    Wwb[i]         = f2bf(Ww[i]);
  }
  for (int i = t; i < 128; i += nthr){
    biasc[i] = bt[i] * LOG2E; biasc[128+i] = bp[i]; biasc[256+i] = bg[i];
  }
  for (int i = t; i < 512; i += nthr) stats[i] = 0.f;
}

// ---------------- K1: fused transpose + 3 projections ----------------
__global__ __launch_bounds__(256) void k1_proj(const float* __restrict__ x,
     const u16* __restrict__ Wcat, const float* __restrict__ biasc,
     u16* __restrict__ theta, u16* __restrict__ kproj, u16* __restrict__ gT){
  __shared__ u16 At[64*264];
  __shared__ u16 Wt_[32*264];
  __shared__ u16 gbuf[32*72];
  int tid = threadIdx.x;
  int b  = blockIdx.x >> 7;
  int nb = (blockIdx.x & 127) * 64;
  int w = tid >> 6, lane = tid & 63;
  int l15 = lane & 15, kg = lane >> 4;

  {
    int cp = tid & 127, nh = tid >> 7;
    int c0 = cp*2;
    const float* src0 = x + ((size_t)(b*C_ + c0))*N_ + nb + nh*32;
    const float* src1 = src0 + N_;
#pragma unroll
    for (int j=0;j<8;j++){
      f32x4 a = *(const f32x4*)(src0 + j*4);
      f32x4 c = *(const f32x4*)(src1 + j*4);
#pragma unroll
      for (int q=0;q<4;q++){
        unsigned pk = (unsigned)f2bf(a[q]) | ((unsigned)f2bf(c[q])<<16);
        *(unsigned*)&At[(nh*32 + j*4 + q)*264 + c0] = pk;
      }
    }
  }
  __syncthreads();

  bf16x8 afr[8];
#pragma unroll
  for (int kc=0;kc<8;kc++)
    afr[kc] = *(const bf16x8*)&At[(w*16+l15)*264 + kc*32 + kg*8];

  for (int och = 0; och < 12; och++){
    {
      int o8 = tid>>3, cp8 = tid&7;
      const u16* wsrc = Wcat + ((size_t)(och*32 + o8))*256 + cp8*8;
#pragma unroll
      for (int j=0;j<4;j++)
        *(u16x8*)&Wt_[o8*264 + cp8*8 + j*64] = *(const u16x8*)(wsrc + j*64);
    }
    __syncthreads();

    f32x4 acc0 = f4zero(), acc1 = f4zero();
#pragma unroll
    for (int kc=0;kc<8;kc++){
      bf16x8 b0 = *(const bf16x8*)&Wt_[(l15)*264 + kc*32 + kg*8];
      bf16x8 b1 = *(const bf16x8*)&Wt_[(16+l15)*264 + kc*32 + kg*8];
      acc0 = mfma16(afr[kc], b0, acc0);
      acc1 = mfma16(afr[kc], b1, acc1);
    }

    if (och < 8){
      u16* dst = (och < 4) ? theta : kproj;
      int oo = (och & 3) * 32;
#pragma unroll
      for (int of=0;of<2;of++){
        int o = oo + of*16 + l15;
        float bias = biasc[och*32 + of*16 + l15];
        f32x4 acc = of ? acc1 : acc0;
#pragma unroll
        for (int i=0;i<4;i++){
          int n = nb + w*16 + kg*4 + i;
          dst[((size_t)b*N_ + n)*CI_ + o] = f2bf(acc[i] + bias);
        }
      }
      __syncthreads();
    } else {
#pragma unroll
      for (int of=0;of<2;of++){
        int o = of*16 + l15;
        float bias = biasc[och*32 + of*16 + l15];
        f32x4 acc = of ? acc1 : acc0;
#pragma unroll
        for (int i=0;i<4;i++){
          int r = w*16 + kg*4 + i;
          gbuf[o*72 + r] = f2bf(acc[i] + bias);
        }
      }
      __syncthreads();
      {
        int o = tid>>3, np = tid&7;
        int og = (och-8)*32 + o;
        u16x8 v = *(const u16x8*)&gbuf[o*72 + np*8];
        *(u16x8*)(gT + ((size_t)b*CI_ + og)*N_ + nb + np*8) = v;
      }
      __syncthreads();
    }
  }
}

// ---------------- K2: flash attention, swapped 32x32 MFMA, KV-split ----------------
// Grid 64*CH blocks x 512 threads (8 waves x 32 q-rows). bid&(2CH-1) = (b,chunk).
// Kt [64 k][128 c] bf16 XOR-swizzled; Vt [128 c][64 k] bf16 XOR-swizzled; dbuf; 64 KB LDS.
template<int CH>
__global__ __launch_bounds__(512, 2) void k2_attn(const u16* __restrict__ theta,
      const u16* __restrict__ kproj, const u16* __restrict__ gT,
      u16* __restrict__ pO, float* __restrict__ pM, float* __restrict__ pL){
  constexpr int CHUNK_N = N_ / CH;
  constexpr int NTI = CHUNK_N / KVB;
  __shared__ char smem[65536];   // [0,32K): Kt dbuf, [32K,64K): Vt dbuf
  char* kbase = smem;
  char* vbase = smem + 32768;
  int tid = threadIdx.x;
  int bid = blockIdx.x;
  int combo = bid & (2*CH - 1);
  int b = combo & 1;
  int chunk = combo >> 1;
  int qblk = bid / (2*CH);             // 0..31
  int n0 = chunk * CHUNK_N;
  int w = tid >> 6, lane = tid & 63;
  int l31 = lane & 31, hi = lane >> 5;
  int qg = qblk*256 + w*32 + l31;

  // Q into registers: lane holds its hi-half of row qg (64 of 128 channels)
  bf16x8 qf[8];
  {
    const u16* qsrc = theta + ((size_t)b*N_ + qg)*CI_ + hi*8;
#pragma unroll
    for (int cc=0; cc<8; cc++) qf[cc] = *(const bf16x8*)(qsrc + cc*16);
  }

  // staging assignment (512 threads, 32 B each per tile per array)
  int krow_s = tid >> 3, kpart = tid & 7;
  int vrow_s = tid >> 2, vpart = tid & 3;
  const u16* ksrc = kproj + ((size_t)b*N_ + n0 + krow_s)*CI_ + kpart*16;
  const u16* vsrc = gT + ((size_t)b*CI_ + vrow_s)*N_ + n0 + vpart*16;
  int kw_off[2], vw_off[2];
#pragma unroll
  for (int j=0;j<2;j++){
    int cb = kpart*32 + j*16;
    kw_off[j] = krow_s*256 + (cb ^ ((krow_s&7)<<4));
    int kb = vpart*32 + j*16;
    vw_off[j] = vrow_s*128 + (kb ^ ((vrow_s&7)<<4));
  }
  // precomputed read offsets (within one buffer)
  int swz = (l31&7)<<4;
  int kro[8], vro[4];
#pragma unroll
  for (int cc=0;cc<8;cc++) kro[cc] = l31*256 + ((cc*32 + hi*16) ^ swz);
#pragma unroll
  for (int ks=0;ks<4;ks++) vro[ks] = l31*128 + ((ks*32 + hi*16) ^ swz);

  // prologue: stage tile 0 into buf0
#pragma unroll
  for (int j=0;j<2;j++){
    *(u16x8*)(kbase + kw_off[j]) = *(const u16x8*)(ksrc + j*8);
    *(u16x8*)(vbase + vw_off[j]) = *(const u16x8*)(vsrc + j*8);
  }
  __syncthreads();

  f32x16 oacc[4];
#pragma unroll
  for (int i=0;i<4;i++) oacc[i] = f16zero();
  float mrun = -1e30f, lrun = 0.f;

  for (int t=0; t<NTI; t++){
    int cur = t & 1;
    char* kb_c = kbase + cur*16384;
    char* vb_c = vbase + cur*16384;
    u16x8 kst[2], vst[2];
    bool pf = (t+1 < NTI);
    if (pf){
      const u16* ks = ksrc + (size_t)(t+1)*KVB*CI_;
      const u16* vs = vsrc + (t+1)*KVB;
#pragma unroll
      for (int j=0;j<2;j++) kst[j] = *(const u16x8*)(ks + j*8);
#pragma unroll
      for (int j=0;j<2;j++) vst[j] = *(const u16x8*)(vs + j*8);
    }

    // --- QK^T (swapped): sA = S^T rows k 0..31, sB rows k 32..63; col = q = l31
    f32x16 sA = f16zero(), sB = f16zero();
    __builtin_amdgcn_s_setprio(1);
#pragma unroll
    for (int cc=0; cc<8; cc++){
      bf16x8 kf0 = *(const bf16x8*)(kb_c + kro[cc]);
      bf16x8 kf1 = *(const bf16x8*)(kb_c + 8192 + kro[cc]);
      sA = mfma32(kf0, qf[cc], sA);
      sB = mfma32(kf1, qf[cc], sB);
    }
    __builtin_amdgcn_s_setprio(0);

    // --- online softmax (exp2 domain), fully in-register
    float t8[8];
#pragma unroll
    for (int i=0;i<8;i++) t8[i] = fmaxf(fmaxf(sA[i], sA[i+8]), fmaxf(sB[i], sB[i+8]));
    float m4a = fmaxf(t8[0], t8[4]), m4b = fmaxf(t8[1], t8[5]);
    float m4c = fmaxf(t8[2], t8[6]), m4d = fmaxf(t8[3], t8[7]);
    float mx = fmaxf(fmaxf(m4a, m4b), fmaxf(m4c, m4d));
    mx = fmaxf(mx, __shfl_xor(mx, 32));
    if (__any(mx > mrun + 12.f)){       // T13 defer-max (12 in log2 units)
      float mnew = fmaxf(mrun, mx);
      float sc = exp2f(mrun - mnew);
      lrun *= sc;
#pragma unroll
      for (int i=0;i<4;i++)
#pragma unroll
        for (int r=0;r<16;r++) oacc[i][r] *= sc;
      mrun = mnew;
    }
    float pA[16], pB[16];
#pragma unroll
    for (int r=0;r<16;r++){ pA[r] = exp2f(sA[r]-mrun); pB[r] = exp2f(sB[r]-mrun); }
    float s8[8];
#pragma unroll
    for (int i=0;i<8;i++) s8[i] = (pA[i]+pA[i+8]) + (pB[i]+pB[i+8]);
    float s4a = s8[0]+s8[4], s4b = s8[1]+s8[5], s4c = s8[2]+s8[6], s4d = s8[3]+s8[7];
    float ps = (s4a+s4b) + (s4c+s4d);
    ps += __shfl_xor(ps, 32);
    lrun += ps;

    // --- T14 write-late: staged regs -> other buffer (overlaps with PV)
    if (pf){
      char* kd = kbase + (cur^1)*16384;
      char* vd = vbase + (cur^1)*16384;
#pragma unroll
      for (int j=0;j<2;j++) *(u16x8*)(kd + kw_off[j]) = kst[j];
#pragma unroll
      for (int j=0;j<2;j++) *(u16x8*)(vd + vw_off[j]) = vst[j];
    }

    // --- PV (swapped): oacc[c2] = O^T chunk rows c, col q = l31
    __builtin_amdgcn_s_setprio(1);
#pragma unroll
    for (int ks=0; ks<4; ks++){
      const float* P = (ks<2) ? pA : pB;
      int r0 = (ks&1)*8;
      unsigned a0 = cvtpk(P[r0+0], P[r0+1]);
      unsigned b0 = cvtpk(P[r0+4], P[r0+5]);
      unsigned a1 = cvtpk(P[r0+2], P[r0+3]);
      unsigned b1 = cvtpk(P[r0+6], P[r0+7]);
      plswap(a0, b0); plswap(a1, b1);
      union { unsigned u[4]; bf16x8 v; } pb;
      pb.u[0]=a0; pb.u[1]=a1; pb.u[2]=b0; pb.u[3]=b1;
#pragma unroll
      for (int c2=0; c2<4; c2++){
        bf16x8 vf = *(const bf16x8*)(vb_c + c2*4096 + vro[ks]);
        oacc[c2] = mfma32(vf, pb.v, oacc[c2]);
      }
    }
    __builtin_amdgcn_s_setprio(0);
    __syncthreads();
  }

  // --- epilogue: O^T -> per-wave LDS region (bf16, swizzled) -> coalesced partial store
  char* region = smem + w*8192;   // 32 q x 128 c bf16 = 8 KB
#pragma unroll
  for (int c2=0;c2<4;c2++)
#pragma unroll
    for (int r=0;r<16;r++){
      int c = c2*32 + (r&3) + 8*(r>>2) + 4*hi;
      *(u16*)(region + l31*256 + ((c*2) ^ swz)) = f2bf(oacc[c2][r]);
    }
  __syncthreads();
  {
    int ql = lane >> 1, half = lane & 1;
    int qg2 = qblk*256 + w*32 + ql;
    u16* dst = pO + ((size_t)(chunk*2 + b)*N_ + qg2)*CI_ + half*64;
    int rswz = (ql&7)<<4;
#pragma unroll
    for (int j=0;j<8;j++){
      u16x8 v2 = *(const u16x8*)(region + ql*256 + ((half*128 + j*16) ^ rswz));
      *(u16x8*)(dst + j*8) = v2;
    }
  }
  if (hi == 0){
    pM[(size_t)(chunk*2 + b)*N_ + qg] = mrun;
    pL[(size_t)(chunk*2 + b)*N_ + qg] = lrun;
  }
}

// ---------------- K2b: combine KV-chunk partials -> y (f32) ----------------
template<int CH>
__global__ __launch_bounds__(256) void k2b_combine(const u16* __restrict__ pO,
    const float* __restrict__ pM, const float* __restrict__ pL,
    float* __restrict__ y){
  int tid = threadIdx.x;
  int blk = blockIdx.x;                // 1024 blocks: b * 512 + qgroup
  int b = blk >> 9;
  int q = (blk & 511) * 16 + (tid >> 4);
  int c0 = (tid & 15) * 8;
  size_t qi = (size_t)b*N_ + q;
  float m[CH], l[CH];
#pragma unroll
  for (int ch=0; ch<CH; ch++){
    m[ch] = pM[(size_t)(ch*2)*N_ + qi];
    l[ch] = pL[(size_t)(ch*2)*N_ + qi];
  }
  float M = m[0];
#pragma unroll
  for (int ch=1; ch<CH; ch++) M = fmaxf(M, m[ch]);
  float wts[CH];
  float L = 0.f;
#pragma unroll
  for (int ch=0; ch<CH; ch++){ wts[ch] = exp2f(m[ch]-M); L += wts[ch]*l[ch]; }
  float inv = 1.f/L;
  float acc[8];
#pragma unroll
  for (int i=0;i<8;i++) acc[i]=0.f;
  const u16* src = pO + qi*CI_ + c0;
#pragma unroll
  for (int ch=0; ch<CH; ch++){
    u16x8 v = *(const u16x8*)(src + (size_t)ch*2*N_*CI_);
#pragma unroll
    for (int i=0;i<8;i++) acc[i] += wts[ch]*bf2f(v[i]);
  }
  float* dst = y + qi*CI_ + c0;
  f32x4 o0, o1;
#pragma unroll
  for (int i=0;i<4;i++){ o0[i] = acc[i]*inv; o1[i] = acc[4+i]*inv; }
  *(f32x4*)dst = o0;
  *(f32x4*)(dst+4) = o1;
}

// ---------------- K3: wy = Ww @ y + bw, plus per-channel sum/sumsq ----------------
__global__ __launch_bounds__(256) void k3_wy(const float* __restrict__ y,
    const u16* __restrict__ Wwb, const float* __restrict__ bw,
    float* __restrict__ wy, float* __restrict__ stats){
  __shared__ u16 Yt[64*136];
  __shared__ u16 Wt_[64*136];
  __shared__ float wyb[64*72];
  int tid = threadIdx.x;
  int b  = blockIdx.x >> 7;
  int nb = (blockIdx.x & 127) * 64;
  int w = tid>>6, lane = tid&63;
  int l15 = lane&15, kg = lane>>4;

  {
    int n = tid>>2, cp = tid&3;
    const float* src = y + ((size_t)b*N_ + nb + n)*CI_ + cp*32;
#pragma unroll
    for (int j=0;j<8;j++){
      f32x4 v = *(const f32x4*)(src + j*4);
      unsigned p0 = (unsigned)f2bf(v[0]) | ((unsigned)f2bf(v[1])<<16);
      unsigned p1 = (unsigned)f2bf(v[2]) | ((unsigned)f2bf(v[3])<<16);
      *(unsigned*)&Yt[n*136 + cp*32 + j*4]     = p0;
      *(unsigned*)&Yt[n*136 + cp*32 + j*4 + 2] = p1;
    }
  }
  __syncthreads();

  bf16x8 afr[4];
#pragma unroll
  for (int kc=0;kc<4;kc++)
    afr[kc] = *(const bf16x8*)&Yt[(w*16+l15)*136 + kc*32 + kg*8];

  for (int oc=0; oc<4; oc++){
    {
      int o = tid>>2, cp = tid&3;
      const u16* src = Wwb + ((size_t)(oc*64 + o))*CI_ + cp*32;
#pragma unroll
      for (int j=0;j<4;j++)
        *(u16x8*)&Wt_[o*136 + cp*32 + j*8] = *(const u16x8*)(src + j*8);
    }
    __syncthreads();

    f32x4 acc[4];
#pragma unroll
    for (int of=0;of<4;of++) acc[of] = f4zero();
#pragma unroll
    for (int kc=0;kc<4;kc++){
#pragma unroll
      for (int of=0;of<4;of++){
        bf16x8 bfr = *(const bf16x8*)&Wt_[(of*16+l15)*136 + kc*32 + kg*8];
        acc[of] = mfma16(afr[kc], bfr, acc[of]);
      }
    }
#pragma unroll
    for (int of=0;of<4;of++){
#pragma unroll
      for (int i=0;i<4;i++)
        wyb[(of*16+l15)*72 + w*16 + kg*4 + i] = acc[of][i];
    }
    __syncthreads();
    {
      int o = tid>>2, np = tid&3;
      int og = oc*64 + o;
      float bias = bw[og];
      float sm = 0.f, sq = 0.f;
      float* dst = wy + ((size_t)b*C_ + og)*N_ + nb + np*16;
#pragma unroll
      for (int j=0;j<4;j++){
        f32x4 v;
#pragma unroll
        for (int q=0;q<4;q++){
          float t2 = wyb[o*72 + np*16 + j*4 + q] + bias;
          v[q] = t2; sm += t2; sq += t2*t2;
        }
        *(f32x4*)(dst + j*4) = v;
      }
      sm += __shfl_xor(sm, 1); sm += __shfl_xor(sm, 2);
      sq += __shfl_xor(sq, 1); sq += __shfl_xor(sq, 2);
      if ((tid&3)==0){
        atomicAdd(&stats[og], sm);
        atomicAdd(&stats[256+og], sq);
      }
    }
    __syncthreads();
  }
}

// ---------------- K4: BN (batch stats) + residual ----------------
__global__ __launch_bounds__(256) void k4_bn(const float* __restrict__ wy,
    const float* __restrict__ x, const float* __restrict__ stats,
    const float* __restrict__ gamma, const float* __restrict__ beta,
    float* __restrict__ out){
  size_t base = ((size_t)blockIdx.x)*2048 + (size_t)threadIdx.x*8;
  int o = (int)((base >> 13) & 255);
  const float invn = 1.f/16384.f;
  float mean = stats[o]*invn;
  float var  = stats[256+o]*invn - mean*mean;
  float rs = rsqrtf(var + 1e-5f);
  float g = gamma[o]*rs;
  float bb = beta[o];
  f32x4 a0 = *(const f32x4*)(wy + base);
  f32x4 a1 = *(const f32x4*)(wy + base + 4);
  f32x4 x0 = *(const f32x4*)(x + base);
  f32x4 x1 = *(const f32x4*)(x + base + 4);
  f32x4 r0, r1;
#pragma unroll
  for (int q=0;q<4;q++){
    r0[q] = (a0[q]-mean)*g + bb + x0[q];
    r1[q] = (a1[q]-mean)*g + bb + x1[q];
  }
  *(f32x4*)(out + base)     = r0;
  *(f32x4*)(out + base + 4) = r1;
}

extern "C" void kernel_launch(void* const* d_in, const int* in_sizes, int n_in,
                              void* d_out, int out_size, void* d_ws, size_t ws_size,
                              hipStream_t stream){
  const float* x     = (const float*)d_in[0];
  const float* Wt    = (const float*)d_in[1];
  const float* bt    = (const float*)d_in[2];
  const float* Wp    = (const float*)d_in[3];
  const float* bp    = (const float*)d_in[4];
  const float* Wg    = (const float*)d_in[5];
  const float* bg    = (const float*)d_in[6];
  const float* Ww    = (const float*)d_in[7];
  const float* bw    = (const float*)d_in[8];
  const float* gamma = (const float*)d_in[9];
  const float* beta  = (const float*)d_in[10];

  // big layout (CH=8) needs: 12M proj + 32M pO + 1M pM/pL + ~264K weights = ~47.5MB
  const size_t BIG_NEED = 47451648;
  bool big = (ws_size >= BIG_NEED);

  char* ws = (char*)d_ws;
  u16*   theta = (u16*)(ws + 0);
  u16*   kproj = (u16*)(ws + 4194304);
  u16*   gT    = (u16*)(ws + 8388608);
  u16*   pO    = (u16*)(ws + 12582912);
  size_t po_bytes = big ? (size_t)33554432 : (size_t)16777216;
  char*  tail  = ws + 12582912 + po_bytes;
  float* pM    = (float*)(tail);
  size_t ml_bytes = big ? (size_t)524288 : (size_t)262144;
  float* pL    = (float*)(tail + ml_bytes);
  u16*   Wcat  = (u16*)(tail + 2*ml_bytes);
  u16*   Wwb   = (u16*)(tail + 2*ml_bytes + 196608);
  float* biasc = (float*)(tail + 2*ml_bytes + 262144);
  float* stats = (float*)(tail + 2*ml_bytes + 263680);
  float* y     = (float*)(ws + 0);          // aliases theta+kproj (dead after k2)
  float* wy    = (float*)(ws + 12582912);   // aliases pO (dead after k2b)
  float* out   = (float*)d_out;

  k0_prep<<<64, 256, 0, stream>>>(Wt, Wp, Wg, Ww, bt, bp, bg, Wcat, Wwb, biasc, stats);
  k1_proj<<<256, 256, 0, stream>>>(x, Wcat, biasc, theta, kproj, gT);
  if (big){
    k2_attn<8><<<512, 512, 0, stream>>>(theta, kproj, gT, pO, pM, pL);
    k2b_combine<8><<<1024, 256, 0, stream>>>(pO, pM, pL, y);
  } else {
    k2_attn<4><<<256, 512, 0, stream>>>(theta, kproj, gT, pO, pM, pL);
    k2b_combine<4><<<1024, 256, 0, stream>>>(pO, pM, pL, y);
  }
  k3_wy<<<256, 256, 0, stream>>>(y, Wwb, bw, wy, stats);
  k4_bn<<<2048, 256, 0, stream>>>(wy, x, stats, gamma, beta, out);
}

// Round 5
// 145.576 us; speedup vs baseline: 2.0677x; 1.1195x over previous
//
#include <hip/hip_runtime.h>
#include <cstdint>
#include <cstddef>

// NonLocalBlock3D: B=2, C=256, Ci=128, N=D*H*W=8192.
// k0 prep -> k1 projections -> k2 flash attention (CH=4 KV-split, 4-wave blocks,
// 2 blocks/CU for barrier decorrelation) -> k3 combine+wy GEMM+stats -> k4 BN+residual.
// Softmax in exp2 domain (log2e folded into Wt/bt).
// NOTE (R3 post-mortem): never request >2 blocks via launch_bounds min-waves on k2 —
// VGPR cap below ~190 unified regs spills ~600 MB scratch. (256,2) caps at 256: safe.
// NOTE (R4 post-mortem): unified reg use ~160-190/wave (oacc=64 AGPR not in VGPR_Count);
// 8-wave blocks can never double up on a CU. 4-wave blocks can (2 waves/SIMD total).

typedef unsigned short u16;
typedef __bf16 bf16x8 __attribute__((ext_vector_type(8)));
typedef float f32x4 __attribute__((ext_vector_type(4)));
typedef float f32x16 __attribute__((ext_vector_type(16)));
typedef unsigned short u16x8 __attribute__((ext_vector_type(8)));

#define B_ 2
#define C_ 256
#define CI_ 128
#define N_ 8192
#define KVB 64

static __device__ __forceinline__ u16 f2bf(float f){
  unsigned u = __builtin_bit_cast(unsigned, f);
  unsigned r = (u + 0x7FFFu + ((u>>16)&1u)) >> 16;
  return (u16)r;
}
static __device__ __forceinline__ float bf2f(u16 v){
  unsigned u = ((unsigned)v) << 16;
  return __builtin_bit_cast(float, u);
}
static __device__ __forceinline__ f32x4 f4zero(){
  f32x4 v; v[0]=0.f; v[1]=0.f; v[2]=0.f; v[3]=0.f; return v;
}
static __device__ __forceinline__ f32x16 f16zero(){
  f32x16 v;
#pragma unroll
  for (int i=0;i<16;i++) v[i]=0.f;
  return v;
}
static __device__ __forceinline__ f32x4 mfma16(bf16x8 a, bf16x8 b, f32x4 c){
  return __builtin_amdgcn_mfma_f32_16x16x32_bf16(a, b, c, 0, 0, 0);
}
static __device__ __forceinline__ f32x16 mfma32(bf16x8 a, bf16x8 b, f32x16 c){
  return __builtin_amdgcn_mfma_f32_32x32x16_bf16(a, b, c, 0, 0, 0);
}
static __device__ __forceinline__ unsigned cvtpk(float lo, float hi){
  unsigned r;
  asm("v_cvt_pk_bf16_f32 %0, %1, %2" : "=v"(r) : "v"(lo), "v"(hi));
  return r;
}
static __device__ __forceinline__ void plswap(unsigned &a, unsigned &b){
  asm volatile("v_permlane32_swap_b32 %0, %1" : "+v"(a), "+v"(b));
}

#define LOG2E 1.4426950408889634f

// ---------------- K0: weight pack (fp32 -> bf16), bias concat, zero stats ----------------
__global__ void k0_prep(const float* __restrict__ Wt, const float* __restrict__ Wp,
                        const float* __restrict__ Wg, const float* __restrict__ Ww,
                        const float* __restrict__ bt, const float* __restrict__ bp,
                        const float* __restrict__ bg,
                        u16* __restrict__ Wcat, u16* __restrict__ Wwb,
                        float* __restrict__ biasc, float* __restrict__ stats){
  int t = blockIdx.x*blockDim.x + threadIdx.x;
  int nthr = gridDim.x*blockDim.x;
  for (int i = t; i < 32768; i += nthr){
    Wcat[i]        = f2bf(Wt[i] * LOG2E);
    Wcat[32768+i]  = f2bf(Wp[i]);
    Wcat[65536+i]  = f2bf(Wg[i]);
    Wwb[i]         = f2bf(Ww[i]);
  }
  for (int i = t; i < 128; i += nthr){
    biasc[i] = bt[i] * LOG2E; biasc[128+i] = bp[i]; biasc[256+i] = bg[i];
  }
  for (int i = t; i < 512; i += nthr) stats[i] = 0.f;
}

// ---------------- K1: fused transpose + 3 projections ----------------
__global__ __launch_bounds__(256) void k1_proj(const float* __restrict__ x,
     const u16* __restrict__ Wcat, const float* __restrict__ biasc,
     u16* __restrict__ theta, u16* __restrict__ kproj, u16* __restrict__ gT){
  __shared__ u16 At[64*264];
  __shared__ u16 Wt_[32*264];
  __shared__ u16 gbuf[32*72];
  int tid = threadIdx.x;
  int b  = blockIdx.x >> 7;
  int nb = (blockIdx.x & 127) * 64;
  int w = tid >> 6, lane = tid & 63;
  int l15 = lane & 15, kg = lane >> 4;

  {
    int cp = tid & 127, nh = tid >> 7;
    int c0 = cp*2;
    const float* src0 = x + ((size_t)(b*C_ + c0))*N_ + nb + nh*32;
    const float* src1 = src0 + N_;
#pragma unroll
    for (int j=0;j<8;j++){
      f32x4 a = *(const f32x4*)(src0 + j*4);
      f32x4 c = *(const f32x4*)(src1 + j*4);
#pragma unroll
      for (int q=0;q<4;q++){
        unsigned pk = (unsigned)f2bf(a[q]) | ((unsigned)f2bf(c[q])<<16);
        *(unsigned*)&At[(nh*32 + j*4 + q)*264 + c0] = pk;
      }
    }
  }
  __syncthreads();

  bf16x8 afr[8];
#pragma unroll
  for (int kc=0;kc<8;kc++)
    afr[kc] = *(const bf16x8*)&At[(w*16+l15)*264 + kc*32 + kg*8];

  for (int och = 0; och < 12; och++){
    {
      int o8 = tid>>3, cp8 = tid&7;
      const u16* wsrc = Wcat + ((size_t)(och*32 + o8))*256 + cp8*8;
#pragma unroll
      for (int j=0;j<4;j++)
        *(u16x8*)&Wt_[o8*264 + cp8*8 + j*64] = *(const u16x8*)(wsrc + j*64);
    }
    __syncthreads();

    f32x4 acc0 = f4zero(), acc1 = f4zero();
#pragma unroll
    for (int kc=0;kc<8;kc++){
      bf16x8 b0 = *(const bf16x8*)&Wt_[(l15)*264 + kc*32 + kg*8];
      bf16x8 b1 = *(const bf16x8*)&Wt_[(16+l15)*264 + kc*32 + kg*8];
      acc0 = mfma16(afr[kc], b0, acc0);
      acc1 = mfma16(afr[kc], b1, acc1);
    }

    if (och < 8){
      u16* dst = (och < 4) ? theta : kproj;
      int oo = (och & 3) * 32;
#pragma unroll
      for (int of=0;of<2;of++){
        int o = oo + of*16 + l15;
        float bias = biasc[och*32 + of*16 + l15];
        f32x4 acc = of ? acc1 : acc0;
#pragma unroll
        for (int i=0;i<4;i++){
          int n = nb + w*16 + kg*4 + i;
          dst[((size_t)b*N_ + n)*CI_ + o] = f2bf(acc[i] + bias);
        }
      }
      __syncthreads();
    } else {
#pragma unroll
      for (int of=0;of<2;of++){
        int o = of*16 + l15;
        float bias = biasc[och*32 + of*16 + l15];
        f32x4 acc = of ? acc1 : acc0;
#pragma unroll
        for (int i=0;i<4;i++){
          int r = w*16 + kg*4 + i;
          gbuf[o*72 + r] = f2bf(acc[i] + bias);
        }
      }
      __syncthreads();
      {
        int o = tid>>3, np = tid&7;
        int og = (och-8)*32 + o;
        u16x8 v = *(const u16x8*)&gbuf[o*72 + np*8];
        *(u16x8*)(gT + ((size_t)b*CI_ + og)*N_ + nb + np*8) = v;
      }
      __syncthreads();
    }
  }
}

// ---------------- K2: flash attention, swapped 32x32 MFMA, CH=4 KV-split ----------------
// Grid 512 blocks x 256 threads (4 waves x 32 q-rows = 128 q/block). bid&7 = (b,chunk).
// 2 blocks/CU co-resident (independent barriers -> MFMA/VALU phase decorrelation).
// Kt [64 k][128 c] XOR-swizzled; Vt [128 c][64 k] XOR-swizzled; dbuf; 64 KB LDS.
__global__ __launch_bounds__(256, 2) void k2_attn(const u16* __restrict__ theta,
      const u16* __restrict__ kproj, const u16* __restrict__ gT,
      u16* __restrict__ pO, float* __restrict__ pM, float* __restrict__ pL){
  constexpr int CHUNK_N = 2048;
  constexpr int NTI = CHUNK_N / KVB;   // 32
  __shared__ char smem[65536];   // [0,32K): Kt dbuf, [32K,64K): Vt dbuf
  char* kbase = smem;
  char* vbase = smem + 32768;
  int tid = threadIdx.x;
  int bid = blockIdx.x;
  int combo = bid & 7;
  int b = combo & 1;
  int chunk = combo >> 1;
  int qblk = bid >> 3;                 // 0..63
  int n0 = chunk * CHUNK_N;
  int w = tid >> 6, lane = tid & 63;
  int l31 = lane & 31, hi = lane >> 5;
  int qg = qblk*128 + w*32 + l31;

  // Q into registers: lane holds its hi-half of row qg (64 of 128 channels)
  bf16x8 qf[8];
  {
    const u16* qsrc = theta + ((size_t)b*N_ + qg)*CI_ + hi*8;
#pragma unroll
    for (int cc=0; cc<8; cc++) qf[cc] = *(const bf16x8*)(qsrc + cc*16);
  }

  // staging assignment (256 threads, 64 B each per tile per array)
  int krow_s = tid >> 2, kpart = tid & 3;
  int vrow_s = tid >> 1, vpart = tid & 1;
  const u16* ksrc = kproj + ((size_t)b*N_ + n0 + krow_s)*CI_ + kpart*32;
  const u16* vsrc = gT + ((size_t)b*CI_ + vrow_s)*N_ + n0 + vpart*32;
  int kw_off[4], vw_off[4];
#pragma unroll
  for (int j=0;j<4;j++){
    kw_off[j] = krow_s*256 + ((kpart*64 + j*16) ^ ((krow_s&7)<<4));
    vw_off[j] = vrow_s*128 + ((vpart*64 + j*16) ^ ((vrow_s&7)<<4));
  }
  // precomputed read offsets (within one buffer)
  int swz = (l31&7)<<4;
  int kro[8], vro[4];
#pragma unroll
  for (int cc=0;cc<8;cc++) kro[cc] = l31*256 + ((cc*32 + hi*16) ^ swz);
#pragma unroll
  for (int ks=0;ks<4;ks++) vro[ks] = l31*128 + ((ks*32 + hi*16) ^ swz);

  // prologue: stage tile 0 into buf0
#pragma unroll
  for (int j=0;j<4;j++) *(u16x8*)(kbase + kw_off[j]) = *(const u16x8*)(ksrc + j*8);
#pragma unroll
  for (int j=0;j<4;j++) *(u16x8*)(vbase + vw_off[j]) = *(const u16x8*)(vsrc + j*8);
  __syncthreads();

  f32x16 oacc[4];
#pragma unroll
  for (int i=0;i<4;i++) oacc[i] = f16zero();
  float mrun = -1e30f, lrun = 0.f;

  for (int t=0; t<NTI; t++){
    int cur = t & 1;
    char* kb_c = kbase + cur*16384;
    char* vb_c = vbase + cur*16384;
    u16x8 kst[4], vst[4];
    bool pf = (t+1 < NTI);
    if (pf){
      const u16* ks = ksrc + (size_t)(t+1)*KVB*CI_;
      const u16* vs = vsrc + (t+1)*KVB;
#pragma unroll
      for (int j=0;j<4;j++) kst[j] = *(const u16x8*)(ks + j*8);
#pragma unroll
      for (int j=0;j<4;j++) vst[j] = *(const u16x8*)(vs + j*8);
    }

    // --- QK^T (swapped): sA = S^T rows k 0..31, sB rows k 32..63; col = q = l31
    f32x16 sA = f16zero(), sB = f16zero();
    __builtin_amdgcn_s_setprio(1);
#pragma unroll
    for (int cc=0; cc<8; cc++){
      bf16x8 kf0 = *(const bf16x8*)(kb_c + kro[cc]);
      bf16x8 kf1 = *(const bf16x8*)(kb_c + 8192 + kro[cc]);
      sA = mfma32(kf0, qf[cc], sA);
      sB = mfma32(kf1, qf[cc], sB);
    }
    __builtin_amdgcn_s_setprio(0);

    // --- online softmax (exp2 domain), fully in-register
    float t8[8];
#pragma unroll
    for (int i=0;i<8;i++) t8[i] = fmaxf(fmaxf(sA[i], sA[i+8]), fmaxf(sB[i], sB[i+8]));
    float m4a = fmaxf(t8[0], t8[4]), m4b = fmaxf(t8[1], t8[5]);
    float m4c = fmaxf(t8[2], t8[6]), m4d = fmaxf(t8[3], t8[7]);
    float mx = fmaxf(fmaxf(m4a, m4b), fmaxf(m4c, m4d));
    mx = fmaxf(mx, __shfl_xor(mx, 32));
    if (__any(mx > mrun + 12.f)){       // T13 defer-max (12 in log2 units)
      float mnew = fmaxf(mrun, mx);
      float sc = exp2f(mrun - mnew);
      lrun *= sc;
#pragma unroll
      for (int i=0;i<4;i++)
#pragma unroll
        for (int r=0;r<16;r++) oacc[i][r] *= sc;
      mrun = mnew;
    }
    float pA[16], pB[16];
#pragma unroll
    for (int r=0;r<16;r++){ pA[r] = exp2f(sA[r]-mrun); pB[r] = exp2f(sB[r]-mrun); }
    float s8[8];
#pragma unroll
    for (int i=0;i<8;i++) s8[i] = (pA[i]+pA[i+8]) + (pB[i]+pB[i+8]);
    float s4a = s8[0]+s8[4], s4b = s8[1]+s8[5], s4c = s8[2]+s8[6], s4d = s8[3]+s8[7];
    float ps = (s4a+s4b) + (s4c+s4d);
    ps += __shfl_xor(ps, 32);
    lrun += ps;

    // --- T14 write-late: staged regs -> other buffer (overlaps with PV)
    if (pf){
      char* kd = kbase + (cur^1)*16384;
      char* vd = vbase + (cur^1)*16384;
#pragma unroll
      for (int j=0;j<4;j++) *(u16x8*)(kd + kw_off[j]) = kst[j];
#pragma unroll
      for (int j=0;j<4;j++) *(u16x8*)(vd + vw_off[j]) = vst[j];
    }

    // --- PV (swapped): oacc[c2] = O^T chunk rows c, col q = l31
    __builtin_amdgcn_s_setprio(1);
#pragma unroll
    for (int ks=0; ks<4; ks++){
      const float* P = (ks<2) ? pA : pB;
      int r0 = (ks&1)*8;
      unsigned a0 = cvtpk(P[r0+0], P[r0+1]);
      unsigned b0 = cvtpk(P[r0+4], P[r0+5]);
      unsigned a1 = cvtpk(P[r0+2], P[r0+3]);
      unsigned b1 = cvtpk(P[r0+6], P[r0+7]);
      plswap(a0, b0); plswap(a1, b1);
      union { unsigned u[4]; bf16x8 v; } pb;
      pb.u[0]=a0; pb.u[1]=a1; pb.u[2]=b0; pb.u[3]=b1;
#pragma unroll
      for (int c2=0; c2<4; c2++){
        bf16x8 vf = *(const bf16x8*)(vb_c + c2*4096 + vro[ks]);
        oacc[c2] = mfma32(vf, pb.v, oacc[c2]);
      }
    }
    __builtin_amdgcn_s_setprio(0);
    __syncthreads();
  }

  // --- epilogue: O^T -> per-wave LDS region (bf16, swizzled) -> coalesced partial store
  char* region = smem + w*8192;   // 4 waves x 8 KB = 32 KB (reuses K/V buffers)
#pragma unroll
  for (int c2=0;c2<4;c2++)
#pragma unroll
    for (int r=0;r<16;r++){
      int c = c2*32 + (r&3) + 8*(r>>2) + 4*hi;
      *(u16*)(region + l31*256 + ((c*2) ^ swz)) = f2bf(oacc[c2][r]);
    }
  __syncthreads();
  {
    int ql = lane >> 1, half = lane & 1;
    int qg2 = qblk*128 + w*32 + ql;
    u16* dst = pO + ((size_t)(chunk*2 + b)*N_ + qg2)*CI_ + half*64;
    int rswz = (ql&7)<<4;
#pragma unroll
    for (int j=0;j<8;j++){
      u16x8 v2 = *(const u16x8*)(region + ql*256 + ((half*128 + j*16) ^ rswz));
      *(u16x8*)(dst + j*8) = v2;
    }
  }
  if (hi == 0){
    pM[(size_t)(chunk*2 + b)*N_ + qg] = mrun;
    pL[(size_t)(chunk*2 + b)*N_ + qg] = lrun;
  }
}

// ---------------- K3: fused combine(pO chunks) + wy = Ww @ y + bw + stats ----------------
__global__ __launch_bounds__(256) void k3_wy(const u16* __restrict__ pO,
    const float* __restrict__ pM, const float* __restrict__ pL,
    const u16* __restrict__ Wwb, const float* __restrict__ bw,
    u16* __restrict__ wy, float* __restrict__ stats){
  __shared__ u16 Yt[64*136];
  __shared__ u16 Wt_[64*136];
  __shared__ float wyb[64*72];
  int tid = threadIdx.x;
  int b  = blockIdx.x >> 7;
  int nb = (blockIdx.x & 127) * 64;
  int w = tid>>6, lane = tid&63;
  int l15 = lane&15, kg = lane>>4;

  // stage y tile [64 n][128 c]: combine 4 KV-chunk partials -> bf16
  {
    int n = tid>>2, cp = tid&3;
    size_t q = (size_t)nb + n;
    float m[4], l[4];
#pragma unroll
    for (int ch=0; ch<4; ch++){
      m[ch] = pM[(size_t)(ch*2+b)*N_ + q];
      l[ch] = pL[(size_t)(ch*2+b)*N_ + q];
    }
    float M = fmaxf(fmaxf(m[0],m[1]), fmaxf(m[2],m[3]));
    float wts[4]; float L = 0.f;
#pragma unroll
    for (int ch=0; ch<4; ch++){ wts[ch] = exp2f(m[ch]-M); L += wts[ch]*l[ch]; }
    float inv = 1.f/L;
#pragma unroll
    for (int j=0;j<4;j++){
      int c0 = cp*32 + j*8;
      float acc[8];
#pragma unroll
      for (int i=0;i<8;i++) acc[i]=0.f;
#pragma unroll
      for (int ch=0; ch<4; ch++){
        u16x8 v = *(const u16x8*)(pO + ((size_t)(ch*2+b)*N_ + q)*CI_ + c0);
#pragma unroll
        for (int i=0;i<8;i++) acc[i] += wts[ch]*bf2f(v[i]);
      }
#pragma unroll
      for (int i=0;i<4;i++){
        unsigned pk = (unsigned)f2bf(acc[2*i]*inv) | ((unsigned)f2bf(acc[2*i+1]*inv)<<16);
        *(unsigned*)&Yt[n*136 + c0 + 2*i] = pk;
      }
    }
  }
  __syncthreads();

  bf16x8 afr[4];
#pragma unroll
  for (int kc=0;kc<4;kc++)
    afr[kc] = *(const bf16x8*)&Yt[(w*16+l15)*136 + kc*32 + kg*8];

  for (int oc=0; oc<4; oc++){
    {
      int o = tid>>2, cp = tid&3;
      const u16* src = Wwb + ((size_t)(oc*64 + o))*CI_ + cp*32;
#pragma unroll
      for (int j=0;j<4;j++)
        *(u16x8*)&Wt_[o*136 + cp*32 + j*8] = *(const u16x8*)(src + j*8);
    }
    __syncthreads();

    f32x4 acc[4];
#pragma unroll
    for (int of=0;of<4;of++) acc[of] = f4zero();
#pragma unroll
    for (int kc=0;kc<4;kc++){
#pragma unroll
      for (int of=0;of<4;of++){
        bf16x8 bfr = *(const bf16x8*)&Wt_[(of*16+l15)*136 + kc*32 + kg*8];
        acc[of] = mfma16(afr[kc], bfr, acc[of]);
      }
    }
#pragma unroll
    for (int of=0;of<4;of++){
#pragma unroll
      for (int i=0;i<4;i++)
        wyb[(of*16+l15)*72 + w*16 + kg*4 + i] = acc[of][i];
    }
    __syncthreads();
    {
      int o = tid>>2, np = tid&3;
      int og = oc*64 + o;
      float bias = bw[og];
      float sm = 0.f, sq = 0.f;
      u16* dst = wy + ((size_t)b*C_ + og)*N_ + nb + np*16;
      u16 buf[16];
#pragma unroll
      for (int j=0;j<4;j++){
#pragma unroll
        for (int q2=0;q2<4;q2++){
          float t2 = wyb[o*72 + np*16 + j*4 + q2] + bias;
          buf[j*4+q2] = f2bf(t2); sm += t2; sq += t2*t2;
        }
      }
      *(u16x8*)dst = *(const u16x8*)&buf[0];
      *(u16x8*)(dst+8) = *(const u16x8*)&buf[8];
      sm += __shfl_xor(sm, 1); sm += __shfl_xor(sm, 2);
      sq += __shfl_xor(sq, 1); sq += __shfl_xor(sq, 2);
      if ((tid&3)==0){
        atomicAdd(&stats[og], sm);
        atomicAdd(&stats[256+og], sq);
      }
    }
    __syncthreads();
  }
}

// ---------------- K4: BN (batch stats) + residual ----------------
__global__ __launch_bounds__(256) void k4_bn(const u16* __restrict__ wy,
    const float* __restrict__ x, const float* __restrict__ stats,
    const float* __restrict__ gamma, const float* __restrict__ beta,
    float* __restrict__ out){
  size_t base = ((size_t)blockIdx.x)*2048 + (size_t)threadIdx.x*8;
  int o = (int)((base >> 13) & 255);
  const float invn = 1.f/16384.f;
  float mean = stats[o]*invn;
  float var  = stats[256+o]*invn - mean*mean;
  float rs = rsqrtf(var + 1e-5f);
  float g = gamma[o]*rs;
  float bb = beta[o];
  u16x8 a = *(const u16x8*)(wy + base);
  f32x4 x0 = *(const f32x4*)(x + base);
  f32x4 x1 = *(const f32x4*)(x + base + 4);
  f32x4 r0, r1;
#pragma unroll
  for (int q=0;q<4;q++){
    r0[q] = (bf2f(a[q])-mean)*g + bb + x0[q];
    r1[q] = (bf2f(a[4+q])-mean)*g + bb + x1[q];
  }
  *(f32x4*)(out + base)     = r0;
  *(f32x4*)(out + base + 4) = r1;
}

extern "C" void kernel_launch(void* const* d_in, const int* in_sizes, int n_in,
                              void* d_out, int out_size, void* d_ws, size_t ws_size,
                              hipStream_t stream){
  const float* x     = (const float*)d_in[0];
  const float* Wt    = (const float*)d_in[1];
  const float* bt    = (const float*)d_in[2];
  const float* Wp    = (const float*)d_in[3];
  const float* bp    = (const float*)d_in[4];
  const float* Wg    = (const float*)d_in[5];
  const float* bg    = (const float*)d_in[6];
  const float* Ww    = (const float*)d_in[7];
  const float* bw    = (const float*)d_in[8];
  const float* gamma = (const float*)d_in[9];
  const float* beta  = (const float*)d_in[10];

  char* ws = (char*)d_ws;
  // [0,4M) theta | [4M,8M) kproj | [8M,12M) gT           (bf16)
  // [12M, +16M) pO bf16 [4ch][2b][8192][128]
  // then pM (256K), pL (256K), wy bf16 (8M), Wcat, Wwb, biasc, stats  (~38.6 MB total)
  u16*   theta = (u16*)(ws + 0);
  u16*   kproj = (u16*)(ws + 4194304);
  u16*   gT    = (u16*)(ws + 8388608);
  u16*   pO    = (u16*)(ws + 12582912);
  float* pM    = (float*)(ws + 29360128);
  float* pL    = (float*)(ws + 29622272);
  u16*   wy    = (u16*)(ws + 29884416);
  u16*   Wcat  = (u16*)(ws + 38273024);
  u16*   Wwb   = (u16*)(ws + 38469632);
  float* biasc = (float*)(ws + 38535168);
  float* stats = (float*)(ws + 38536704);
  float* out   = (float*)d_out;

  k0_prep<<<64, 256, 0, stream>>>(Wt, Wp, Wg, Ww, bt, bp, bg, Wcat, Wwb, biasc, stats);
  k1_proj<<<256, 256, 0, stream>>>(x, Wcat, biasc, theta, kproj, gT);
  k2_attn<<<512, 256, 0, stream>>>(theta, kproj, gT, pO, pM, pL);
  k3_wy<<<256, 256, 0, stream>>>(pO, pM, pL, Wwb, bw, wy, stats);
  k4_bn<<<2048, 256, 0, stream>>>(wy, x, stats, gamma, beta, out);
}

// Round 6
// 142.850 us; speedup vs baseline: 2.1072x; 1.0191x over previous
//
#include <hip/hip_runtime.h>
#include <cstdint>
#include <cstddef>

// NonLocalBlock3D: B=2, C=256, Ci=128, N=D*H*W=8192.
// k0 prep -> k1 projections -> k2 flash attention (CH=4 KV-split, 512-thr blocks,
// global_load_lds staging w/ pre-swizzled source) -> k3 combine+wy GEMM+stats -> k4 BN+res.
// Softmax in exp2 domain (log2e folded into Wt/bt).
// R3 post-mortem: never cap k2 VGPR below ~190 unified (spills 600 MB scratch). (512,2) safe.
// R4 post-mortem: 8-wave blocks never double up; occupancy ceiling is 8 waves/CU (LDS 64K).
// R5 post-mortem: 128-q blocks double staging traffic; VALU became the binding pipe.
//   -> this round: 256-q blocks + global_load_lds DMA staging (no ds_write, no staging regs).

typedef unsigned short u16;
typedef __bf16 bf16x8 __attribute__((ext_vector_type(8)));
typedef float f32x4 __attribute__((ext_vector_type(4)));
typedef float f32x16 __attribute__((ext_vector_type(16)));
typedef unsigned short u16x8 __attribute__((ext_vector_type(8)));

#define B_ 2
#define C_ 256
#define CI_ 128
#define N_ 8192
#define KVB 64

static __device__ __forceinline__ u16 f2bf(float f){
  unsigned u = __builtin_bit_cast(unsigned, f);
  unsigned r = (u + 0x7FFFu + ((u>>16)&1u)) >> 16;
  return (u16)r;
}
static __device__ __forceinline__ float bf2f(u16 v){
  unsigned u = ((unsigned)v) << 16;
  return __builtin_bit_cast(float, u);
}
static __device__ __forceinline__ f32x4 f4zero(){
  f32x4 v; v[0]=0.f; v[1]=0.f; v[2]=0.f; v[3]=0.f; return v;
}
static __device__ __forceinline__ f32x16 f16zero(){
  f32x16 v;
#pragma unroll
  for (int i=0;i<16;i++) v[i]=0.f;
  return v;
}
static __device__ __forceinline__ f32x4 mfma16(bf16x8 a, bf16x8 b, f32x4 c){
  return __builtin_amdgcn_mfma_f32_16x16x32_bf16(a, b, c, 0, 0, 0);
}
static __device__ __forceinline__ f32x16 mfma32(bf16x8 a, bf16x8 b, f32x16 c){
  return __builtin_amdgcn_mfma_f32_32x32x16_bf16(a, b, c, 0, 0, 0);
}
static __device__ __forceinline__ unsigned cvtpk(float lo, float hi){
  unsigned r;
  asm("v_cvt_pk_bf16_f32 %0, %1, %2" : "=v"(r) : "v"(lo), "v"(hi));
  return r;
}
static __device__ __forceinline__ void plswap(unsigned &a, unsigned &b){
  asm volatile("v_permlane32_swap_b32 %0, %1" : "+v"(a), "+v"(b));
}
static __device__ __forceinline__ void glds16(const void* g, void* l){
  __builtin_amdgcn_global_load_lds((const __attribute__((address_space(1))) void*)g,
                                   (__attribute__((address_space(3))) void*)l, 16, 0, 0);
}

#define LOG2E 1.4426950408889634f

// ---------------- K0: weight pack (fp32 -> bf16), bias concat, zero stats ----------------
__global__ void k0_prep(const float* __restrict__ Wt, const float* __restrict__ Wp,
                        const float* __restrict__ Wg, const float* __restrict__ Ww,
                        const float* __restrict__ bt, const float* __restrict__ bp,
                        const float* __restrict__ bg,
                        u16* __restrict__ Wcat, u16* __restrict__ Wwb,
                        float* __restrict__ biasc, float* __restrict__ stats){
  int t = blockIdx.x*blockDim.x + threadIdx.x;
  int nthr = gridDim.x*blockDim.x;
  for (int i = t; i < 32768; i += nthr){
    Wcat[i]        = f2bf(Wt[i] * LOG2E);
    Wcat[32768+i]  = f2bf(Wp[i]);
    Wcat[65536+i]  = f2bf(Wg[i]);
    Wwb[i]         = f2bf(Ww[i]);
  }
  for (int i = t; i < 128; i += nthr){
    biasc[i] = bt[i] * LOG2E; biasc[128+i] = bp[i]; biasc[256+i] = bg[i];
  }
  for (int i = t; i < 512; i += nthr) stats[i] = 0.f;
}

// ---------------- K1: fused transpose + 3 projections ----------------
__global__ __launch_bounds__(256) void k1_proj(const float* __restrict__ x,
     const u16* __restrict__ Wcat, const float* __restrict__ biasc,
     u16* __restrict__ theta, u16* __restrict__ kproj, u16* __restrict__ gT){
  __shared__ u16 At[64*264];
  __shared__ u16 Wt_[32*264];
  __shared__ u16 gbuf[32*72];
  int tid = threadIdx.x;
  int b  = blockIdx.x >> 7;
  int nb = (blockIdx.x & 127) * 64;
  int w = tid >> 6, lane = tid & 63;
  int l15 = lane & 15, kg = lane >> 4;

  {
    int cp = tid & 127, nh = tid >> 7;
    int c0 = cp*2;
    const float* src0 = x + ((size_t)(b*C_ + c0))*N_ + nb + nh*32;
    const float* src1 = src0 + N_;
#pragma unroll
    for (int j=0;j<8;j++){
      f32x4 a = *(const f32x4*)(src0 + j*4);
      f32x4 c = *(const f32x4*)(src1 + j*4);
#pragma unroll
      for (int q=0;q<4;q++){
        unsigned pk = (unsigned)f2bf(a[q]) | ((unsigned)f2bf(c[q])<<16);
        *(unsigned*)&At[(nh*32 + j*4 + q)*264 + c0] = pk;
      }
    }
  }
  __syncthreads();

  bf16x8 afr[8];
#pragma unroll
  for (int kc=0;kc<8;kc++)
    afr[kc] = *(const bf16x8*)&At[(w*16+l15)*264 + kc*32 + kg*8];

  for (int och = 0; och < 12; och++){
    {
      int o8 = tid>>3, cp8 = tid&7;
      const u16* wsrc = Wcat + ((size_t)(och*32 + o8))*256 + cp8*8;
#pragma unroll
      for (int j=0;j<4;j++)
        *(u16x8*)&Wt_[o8*264 + cp8*8 + j*64] = *(const u16x8*)(wsrc + j*64);
    }
    __syncthreads();

    f32x4 acc0 = f4zero(), acc1 = f4zero();
#pragma unroll
    for (int kc=0;kc<8;kc++){
      bf16x8 b0 = *(const bf16x8*)&Wt_[(l15)*264 + kc*32 + kg*8];
      bf16x8 b1 = *(const bf16x8*)&Wt_[(16+l15)*264 + kc*32 + kg*8];
      acc0 = mfma16(afr[kc], b0, acc0);
      acc1 = mfma16(afr[kc], b1, acc1);
    }

    if (och < 8){
      u16* dst = (och < 4) ? theta : kproj;
      int oo = (och & 3) * 32;
#pragma unroll
      for (int of=0;of<2;of++){
        int o = oo + of*16 + l15;
        float bias = biasc[och*32 + of*16 + l15];
        f32x4 acc = of ? acc1 : acc0;
#pragma unroll
        for (int i=0;i<4;i++){
          int n = nb + w*16 + kg*4 + i;
          dst[((size_t)b*N_ + n)*CI_ + o] = f2bf(acc[i] + bias);
        }
      }
      __syncthreads();
    } else {
#pragma unroll
      for (int of=0;of<2;of++){
        int o = of*16 + l15;
        float bias = biasc[och*32 + of*16 + l15];
        f32x4 acc = of ? acc1 : acc0;
#pragma unroll
        for (int i=0;i<4;i++){
          int r = w*16 + kg*4 + i;
          gbuf[o*72 + r] = f2bf(acc[i] + bias);
        }
      }
      __syncthreads();
      {
        int o = tid>>3, np = tid&7;
        int og = (och-8)*32 + o;
        u16x8 v = *(const u16x8*)&gbuf[o*72 + np*8];
        *(u16x8*)(gT + ((size_t)b*CI_ + og)*N_ + nb + np*8) = v;
      }
      __syncthreads();
    }
  }
}

// ---------------- K2: flash attention, swapped 32x32 MFMA, CH=4 KV-split ----------------
// Grid 256 blocks x 512 threads (8 waves x 32 q-rows = 256 q/block). bid&7 = (b,chunk).
// Staging: global_load_lds width-16, pre-swizzled per-lane SOURCE + linear LDS dest;
// read side applies the same XOR (involution) -> image identical to the proven layout.
__global__ __launch_bounds__(512, 2) void k2_attn(const u16* __restrict__ theta,
      const u16* __restrict__ kproj, const u16* __restrict__ gT,
      u16* __restrict__ pO, float* __restrict__ pM, float* __restrict__ pL){
  constexpr int CHUNK_N = 2048;
  constexpr int NTI = CHUNK_N / KVB;   // 32
  __shared__ char smem[65536];   // [0,32K): Kt dbuf, [32K,64K): Vt dbuf
  char* kbase = smem;
  char* vbase = smem + 32768;
  int tid = threadIdx.x;
  int bid = blockIdx.x;
  int combo = bid & 7;
  int b = combo & 1;
  int chunk = combo >> 1;
  int qblk = bid >> 3;                 // 0..31
  int n0 = chunk * CHUNK_N;
  int w = tid >> 6, lane = tid & 63;
  int l31 = lane & 31, hi = lane >> 5;
  int qg = qblk*256 + w*32 + l31;

  // Q into registers: lane holds its hi-half of row qg (64 of 128 channels)
  bf16x8 qf[8];
  {
    const u16* qsrc = theta + ((size_t)b*N_ + qg)*CI_ + hi*8;
#pragma unroll
    for (int cc=0; cc<8; cc++) qf[cc] = *(const bf16x8*)(qsrc + cc*16);
  }

  // --- DMA staging geometry ---
  // K tile: 64 rows x 256 B. Linear LDS off L=(i*8+w)*1024+lane*16 -> row=L>>8, pos=L&255.
  // LDS(r,pos) must hold global(r, pos ^ ((r&7)<<4)).
  int kr = w*4 + (lane>>4);                         // issue-0 row (issue1: +32, same &7)
  int kcol = ((lane&15)*16) ^ ((kr&7)<<4);
  const char* kg_base = (const char*)kproj + ((size_t)b*N_ + n0 + kr)*256 + kcol;
  char* kd_base = kbase + w*1024;                   // + lane*16 implicit
  // V tile: 128 rows x 128 B. row=L>>7, pos=L&127.
  int vr = w*8 + (lane>>3);                         // issue-0 row (issue1: +64, same &7)
  int vcol = ((lane&7)*16) ^ ((vr&7)<<4);
  const char* vg_base = (const char*)gT + (((size_t)b*CI_ + vr)*N_ + n0)*2 + vcol;
  char* vd_base = vbase + w*1024;

  // read offsets (swizzled)
  int swz = (l31&7)<<4;
  int kro[8], vro[4];
#pragma unroll
  for (int cc=0;cc<8;cc++) kro[cc] = l31*256 + ((cc*32 + hi*16) ^ swz);
#pragma unroll
  for (int ks=0;ks<4;ks++) vro[ks] = l31*128 + ((ks*32 + hi*16) ^ swz);

  // prologue: DMA tile 0 into buf0
  glds16(kg_base, kd_base);
  glds16(kg_base + 8192, kd_base + 8192);           // rows +32
  glds16(vg_base, vd_base);
  glds16(vg_base + (size_t)64*N_*2, vd_base + 8192); // rows +64
  __syncthreads();

  f32x16 oacc[4];
#pragma unroll
  for (int i=0;i<4;i++) oacc[i] = f16zero();
  float mrun = -1e30f, lrun = 0.f;

  for (int t=0; t<NTI; t++){
    int cur = t & 1;
    char* kb_c = kbase + cur*16384;
    char* vb_c = vbase + cur*16384;

    // issue DMA for tile t+1 into the other buffer (previous reads of it done at last barrier)
    if (t+1 < NTI){
      const char* kg = kg_base + (size_t)(t+1)*16384;
      const char* vg = vg_base + (size_t)(t+1)*128;
      char* kd = kd_base + (cur^1)*16384;
      char* vd = vd_base + (cur^1)*16384;
      glds16(kg, kd);
      glds16(kg + 8192, kd + 8192);
      glds16(vg, vd);
      glds16(vg + (size_t)64*N_*2, vd + 8192);
    }

    // --- QK^T (swapped): sA = S^T rows k 0..31, sB rows k 32..63; col = q = l31
    f32x16 sA = f16zero(), sB = f16zero();
    __builtin_amdgcn_s_setprio(1);
#pragma unroll
    for (int cc=0; cc<8; cc++){
      bf16x8 kf0 = *(const bf16x8*)(kb_c + kro[cc]);
      bf16x8 kf1 = *(const bf16x8*)(kb_c + 8192 + kro[cc]);
      sA = mfma32(kf0, qf[cc], sA);
      sB = mfma32(kf1, qf[cc], sB);
    }
    __builtin_amdgcn_s_setprio(0);

    // --- online softmax (exp2 domain), fully in-register
    float t8[8];
#pragma unroll
    for (int i=0;i<8;i++) t8[i] = fmaxf(fmaxf(sA[i], sA[i+8]), fmaxf(sB[i], sB[i+8]));
    float m4a = fmaxf(t8[0], t8[4]), m4b = fmaxf(t8[1], t8[5]);
    float m4c = fmaxf(t8[2], t8[6]), m4d = fmaxf(t8[3], t8[7]);
    float mx = fmaxf(fmaxf(m4a, m4b), fmaxf(m4c, m4d));
    mx = fmaxf(mx, __shfl_xor(mx, 32));
    if (__any(mx > mrun + 12.f)){       // T13 defer-max (12 in log2 units)
      float mnew = fmaxf(mrun, mx);
      float sc = exp2f(mrun - mnew);
      lrun *= sc;
#pragma unroll
      for (int i=0;i<4;i++)
#pragma unroll
        for (int r=0;r<16;r++) oacc[i][r] *= sc;
      mrun = mnew;
    }
    float pA[16], pB[16];
#pragma unroll
    for (int r=0;r<16;r++){ pA[r] = exp2f(sA[r]-mrun); pB[r] = exp2f(sB[r]-mrun); }
    float s8[8];
#pragma unroll
    for (int i=0;i<8;i++) s8[i] = (pA[i]+pA[i+8]) + (pB[i]+pB[i+8]);
    float s4a = s8[0]+s8[4], s4b = s8[1]+s8[5], s4c = s8[2]+s8[6], s4d = s8[3]+s8[7];
    float ps = (s4a+s4b) + (s4c+s4d);
    ps += __shfl_xor(ps, 32);
    lrun += ps;

    // --- PV (swapped): oacc[c2] = O^T chunk rows c, col q = l31
    __builtin_amdgcn_s_setprio(1);
#pragma unroll
    for (int ks=0; ks<4; ks++){
      const float* P = (ks<2) ? pA : pB;
      int r0 = (ks&1)*8;
      unsigned a0 = cvtpk(P[r0+0], P[r0+1]);
      unsigned b0 = cvtpk(P[r0+4], P[r0+5]);
      unsigned a1 = cvtpk(P[r0+2], P[r0+3]);
      unsigned b1 = cvtpk(P[r0+6], P[r0+7]);
      plswap(a0, b0); plswap(a1, b1);
      union { unsigned u[4]; bf16x8 v; } pb;
      pb.u[0]=a0; pb.u[1]=a1; pb.u[2]=b0; pb.u[3]=b1;
#pragma unroll
      for (int c2=0; c2<4; c2++){
        bf16x8 vf = *(const bf16x8*)(vb_c + c2*4096 + vro[ks]);
        oacc[c2] = mfma32(vf, pb.v, oacc[c2]);
      }
    }
    __builtin_amdgcn_s_setprio(0);
    __syncthreads();   // compiler drains vmcnt(0) here -> next tile's DMA complete
  }

  // --- epilogue: O^T -> per-wave LDS region (bf16, swizzled) -> coalesced partial store
  char* region = smem + w*8192;   // 8 waves x 8 KB = 64 KB (reuses K/V buffers)
#pragma unroll
  for (int c2=0;c2<4;c2++)
#pragma unroll
    for (int r=0;r<16;r++){
      int c = c2*32 + (r&3) + 8*(r>>2) + 4*hi;
      *(u16*)(region + l31*256 + ((c*2) ^ swz)) = f2bf(oacc[c2][r]);
    }
  __syncthreads();
  {
    int ql = lane >> 1, half = lane & 1;
    int qg2 = qblk*256 + w*32 + ql;
    u16* dst = pO + ((size_t)(chunk*2 + b)*N_ + qg2)*CI_ + half*64;
    int rswz = (ql&7)<<4;
#pragma unroll
    for (int j=0;j<8;j++){
      u16x8 v2 = *(const u16x8*)(region + ql*256 + ((half*128 + j*16) ^ rswz));
      *(u16x8*)(dst + j*8) = v2;
    }
  }
  if (hi == 0){
    pM[(size_t)(chunk*2 + b)*N_ + qg] = mrun;
    pL[(size_t)(chunk*2 + b)*N_ + qg] = lrun;
  }
}

// ---------------- K3: fused combine(pO chunks) + wy = Ww @ y + bw + stats ----------------
__global__ __launch_bounds__(256) void k3_wy(const u16* __restrict__ pO,
    const float* __restrict__ pM, const float* __restrict__ pL,
    const u16* __restrict__ Wwb, const float* __restrict__ bw,
    u16* __restrict__ wy, float* __restrict__ stats){
  __shared__ u16 Yt[64*136];
  __shared__ u16 Wt_[64*136];
  __shared__ float wyb[64*72];
  int tid = threadIdx.x;
  int b  = blockIdx.x >> 7;
  int nb = (blockIdx.x & 127) * 64;
  int w = tid>>6, lane = tid&63;
  int l15 = lane&15, kg = lane>>4;

  // stage y tile [64 n][128 c]: combine 4 KV-chunk partials -> bf16
  {
    int n = tid>>2, cp = tid&3;
    size_t q = (size_t)nb + n;
    float m[4], l[4];
#pragma unroll
    for (int ch=0; ch<4; ch++){
      m[ch] = pM[(size_t)(ch*2+b)*N_ + q];
      l[ch] = pL[(size_t)(ch*2+b)*N_ + q];
    }
    float M = fmaxf(fmaxf(m[0],m[1]), fmaxf(m[2],m[3]));
    float wts[4]; float L = 0.f;
#pragma unroll
    for (int ch=0; ch<4; ch++){ wts[ch] = exp2f(m[ch]-M); L += wts[ch]*l[ch]; }
    float inv = 1.f/L;
#pragma unroll
    for (int j=0;j<4;j++){
      int c0 = cp*32 + j*8;
      float acc[8];
#pragma unroll
      for (int i=0;i<8;i++) acc[i]=0.f;
#pragma unroll
      for (int ch=0; ch<4; ch++){
        u16x8 v = *(const u16x8*)(pO + ((size_t)(ch*2+b)*N_ + q)*CI_ + c0);
#pragma unroll
        for (int i=0;i<8;i++) acc[i] += wts[ch]*bf2f(v[i]);
      }
#pragma unroll
      for (int i=0;i<4;i++){
        unsigned pk = (unsigned)f2bf(acc[2*i]*inv) | ((unsigned)f2bf(acc[2*i+1]*inv)<<16);
        *(unsigned*)&Yt[n*136 + c0 + 2*i] = pk;
      }
    }
  }
  __syncthreads();

  bf16x8 afr[4];
#pragma unroll
  for (int kc=0;kc<4;kc++)
    afr[kc] = *(const bf16x8*)&Yt[(w*16+l15)*136 + kc*32 + kg*8];

  for (int oc=0; oc<4; oc++){
    {
      int o = tid>>2, cp = tid&3;
      const u16* src = Wwb + ((size_t)(oc*64 + o))*CI_ + cp*32;
#pragma unroll
      for (int j=0;j<4;j++)
        *(u16x8*)&Wt_[o*136 + cp*32 + j*8] = *(const u16x8*)(src + j*8);
    }
    __syncthreads();

    f32x4 acc[4];
#pragma unroll
    for (int of=0;of<4;of++) acc[of] = f4zero();
#pragma unroll
    for (int kc=0;kc<4;kc++){
#pragma unroll
      for (int of=0;of<4;of++){
        bf16x8 bfr = *(const bf16x8*)&Wt_[(of*16+l15)*136 + kc*32 + kg*8];
        acc[of] = mfma16(afr[kc], bfr, acc[of]);
      }
    }
#pragma unroll
    for (int of=0;of<4;of++){
#pragma unroll
      for (int i=0;i<4;i++)
        wyb[(of*16+l15)*72 + w*16 + kg*4 + i] = acc[of][i];
    }
    __syncthreads();
    {
      int o = tid>>2, np = tid&3;
      int og = oc*64 + o;
      float bias = bw[og];
      float sm = 0.f, sq = 0.f;
      u16* dst = wy + ((size_t)b*C_ + og)*N_ + nb + np*16;
      u16 buf[16];
#pragma unroll
      for (int j=0;j<4;j++){
#pragma unroll
        for (int q2=0;q2<4;q2++){
          float t2 = wyb[o*72 + np*16 + j*4 + q2] + bias;
          buf[j*4+q2] = f2bf(t2); sm += t2; sq += t2*t2;
        }
      }
      *(u16x8*)dst = *(const u16x8*)&buf[0];
      *(u16x8*)(dst+8) = *(const u16x8*)&buf[8];
      sm += __shfl_xor(sm, 1); sm += __shfl_xor(sm, 2);
      sq += __shfl_xor(sq, 1); sq += __shfl_xor(sq, 2);
      if ((tid&3)==0){
        atomicAdd(&stats[og], sm);
        atomicAdd(&stats[256+og], sq);
      }
    }
    __syncthreads();
  }
}

// ---------------- K4: BN (batch stats) + residual ----------------
__global__ __launch_bounds__(256) void k4_bn(const u16* __restrict__ wy,
    const float* __restrict__ x, const float* __restrict__ stats,
    const float* __restrict__ gamma, const float* __restrict__ beta,
    float* __restrict__ out){
  size_t base = ((size_t)blockIdx.x)*2048 + (size_t)threadIdx.x*8;
  int o = (int)((base >> 13) & 255);
  const float invn = 1.f/16384.f;
  float mean = stats[o]*invn;
  float var  = stats[256+o]*invn - mean*mean;
  float rs = rsqrtf(var + 1e-5f);
  float g = gamma[o]*rs;
  float bb = beta[o];
  u16x8 a = *(const u16x8*)(wy + base);
  f32x4 x0 = *(const f32x4*)(x + base);
  f32x4 x1 = *(const f32x4*)(x + base + 4);
  f32x4 r0, r1;
#pragma unroll
  for (int q=0;q<4;q++){
    r0[q] = (bf2f(a[q])-mean)*g + bb + x0[q];
    r1[q] = (bf2f(a[4+q])-mean)*g + bb + x1[q];
  }
  *(f32x4*)(out + base)     = r0;
  *(f32x4*)(out + base + 4) = r1;
}

extern "C" void kernel_launch(void* const* d_in, const int* in_sizes, int n_in,
                              void* d_out, int out_size, void* d_ws, size_t ws_size,
                              hipStream_t stream){
  const float* x     = (const float*)d_in[0];
  const float* Wt    = (const float*)d_in[1];
  const float* bt    = (const float*)d_in[2];
  const float* Wp    = (const float*)d_in[3];
  const float* bp    = (const float*)d_in[4];
  const float* Wg    = (const float*)d_in[5];
  const float* bg    = (const float*)d_in[6];
  const float* Ww    = (const float*)d_in[7];
  const float* bw    = (const float*)d_in[8];
  const float* gamma = (const float*)d_in[9];
  const float* beta  = (const float*)d_in[10];

  char* ws = (char*)d_ws;
  // [0,4M) theta | [4M,8M) kproj | [8M,12M) gT           (bf16)
  // [12M, +16M) pO bf16 [4ch][2b][8192][128]
  // then pM (256K), pL (256K), wy bf16 (8M), Wcat, Wwb, biasc, stats  (~36.8 MiB total)
  u16*   theta = (u16*)(ws + 0);
  u16*   kproj = (u16*)(ws + 4194304);
  u16*   gT    = (u16*)(ws + 8388608);
  u16*   pO    = (u16*)(ws + 12582912);
  float* pM    = (float*)(ws + 29360128);
  float* pL    = (float*)(ws + 29622272);
  u16*   wy    = (u16*)(ws + 29884416);
  u16*   Wcat  = (u16*)(ws + 38273024);
  u16*   Wwb   = (u16*)(ws + 38469632);
  float* biasc = (float*)(ws + 38535168);
  float* stats = (float*)(ws + 38536704);
  float* out   = (float*)d_out;

  k0_prep<<<64, 256, 0, stream>>>(Wt, Wp, Wg, Ww, bt, bp, bg, Wcat, Wwb, biasc, stats);
  k1_proj<<<256, 256, 0, stream>>>(x, Wcat, biasc, theta, kproj, gT);
  k2_attn<<<256, 512, 0, stream>>>(theta, kproj, gT, pO, pM, pL);
  k3_wy<<<256, 256, 0, stream>>>(pO, pM, pL, Wwb, bw, wy, stats);
  k4_bn<<<2048, 256, 0, stream>>>(wy, x, stats, gamma, beta, out);
}

// Round 7
// 142.325 us; speedup vs baseline: 2.1149x; 1.0037x over previous
//
#include <hip/hip_runtime.h>
#include <cstdint>
#include <cstddef>

// NonLocalBlock3D: B=2, C=256, Ci=128, N=D*H*W=8192.
// k0 prep -> k1 projections -> k2 flash attention (CH=4 KV-split, 512-thr blocks,
// reg-staged write-late dbuf — the R2-proven structure) -> k3 combine+wy GEMM+stats -> k4 BN+res.
// Softmax in exp2 domain (log2e folded into Wt/bt).
// R3: never cap k2 VGPR via launch_bounds min-waves (spills 600 MB scratch). (512,2) safe.
// R4: 8-wave blocks can't double up (unified regs ~160/wave); ceiling 8 waves/CU here.
// R5: 128-q blocks double staging traffic -> VALU-bound. Keep 256-q blocks.
// R6: global_load_lds staging REGRESSED (93->108us): compiler serializes DMA vs ds_read
//     (latency on critical path). Keep reg-staged global->VGPR->LDS write-late.

typedef unsigned short u16;
typedef __bf16 bf16x8 __attribute__((ext_vector_type(8)));
typedef float f32x4 __attribute__((ext_vector_type(4)));
typedef float f32x16 __attribute__((ext_vector_type(16)));
typedef unsigned short u16x8 __attribute__((ext_vector_type(8)));

#define B_ 2
#define C_ 256
#define CI_ 128
#define N_ 8192
#define KVB 64

static __device__ __forceinline__ u16 f2bf(float f){
  unsigned u = __builtin_bit_cast(unsigned, f);
  unsigned r = (u + 0x7FFFu + ((u>>16)&1u)) >> 16;
  return (u16)r;
}
static __device__ __forceinline__ float bf2f(u16 v){
  unsigned u = ((unsigned)v) << 16;
  return __builtin_bit_cast(float, u);
}
static __device__ __forceinline__ f32x4 f4zero(){
  f32x4 v; v[0]=0.f; v[1]=0.f; v[2]=0.f; v[3]=0.f; return v;
}
static __device__ __forceinline__ f32x16 f16zero(){
  f32x16 v;
#pragma unroll
  for (int i=0;i<16;i++) v[i]=0.f;
  return v;
}
static __device__ __forceinline__ f32x4 mfma16(bf16x8 a, bf16x8 b, f32x4 c){
  return __builtin_amdgcn_mfma_f32_16x16x32_bf16(a, b, c, 0, 0, 0);
}
static __device__ __forceinline__ f32x16 mfma32(bf16x8 a, bf16x8 b, f32x16 c){
  return __builtin_amdgcn_mfma_f32_32x32x16_bf16(a, b, c, 0, 0, 0);
}
static __device__ __forceinline__ unsigned cvtpk(float lo, float hi){
  unsigned r;
  asm("v_cvt_pk_bf16_f32 %0, %1, %2" : "=v"(r) : "v"(lo), "v"(hi));
  return r;
}
static __device__ __forceinline__ void plswap(unsigned &a, unsigned &b){
  asm volatile("v_permlane32_swap_b32 %0, %1" : "+v"(a), "+v"(b));
}

#define LOG2E 1.4426950408889634f

// ---------------- K0: weight pack (fp32 -> bf16), bias concat, zero stats ----------------
__global__ void k0_prep(const float* __restrict__ Wt, const float* __restrict__ Wp,
                        const float* __restrict__ Wg, const float* __restrict__ Ww,
                        const float* __restrict__ bt, const float* __restrict__ bp,
                        const float* __restrict__ bg,
                        u16* __restrict__ Wcat, u16* __restrict__ Wwb,
                        float* __restrict__ biasc, float* __restrict__ stats){
  int t = blockIdx.x*blockDim.x + threadIdx.x;
  int nthr = gridDim.x*blockDim.x;
  for (int i = t; i < 32768; i += nthr){
    Wcat[i]        = f2bf(Wt[i] * LOG2E);
    Wcat[32768+i]  = f2bf(Wp[i]);
    Wcat[65536+i]  = f2bf(Wg[i]);
    Wwb[i]         = f2bf(Ww[i]);
  }
  for (int i = t; i < 128; i += nthr){
    biasc[i] = bt[i] * LOG2E; biasc[128+i] = bp[i]; biasc[256+i] = bg[i];
  }
  for (int i = t; i < 512; i += nthr) stats[i] = 0.f;
}

// ---------------- K1: fused transpose + 3 projections ----------------
__global__ __launch_bounds__(256) void k1_proj(const float* __restrict__ x,
     const u16* __restrict__ Wcat, const float* __restrict__ biasc,
     u16* __restrict__ theta, u16* __restrict__ kproj, u16* __restrict__ gT){
  __shared__ u16 At[64*264];
  __shared__ u16 Wt_[32*264];
  __shared__ u16 gbuf[32*72];
  int tid = threadIdx.x;
  int b  = blockIdx.x >> 7;
  int nb = (blockIdx.x & 127) * 64;
  int w = tid >> 6, lane = tid & 63;
  int l15 = lane & 15, kg = lane >> 4;

  {
    int cp = tid & 127, nh = tid >> 7;
    int c0 = cp*2;
    const float* src0 = x + ((size_t)(b*C_ + c0))*N_ + nb + nh*32;
    const float* src1 = src0 + N_;
#pragma unroll
    for (int j=0;j<8;j++){
      f32x4 a = *(const f32x4*)(src0 + j*4);
      f32x4 c = *(const f32x4*)(src1 + j*4);
#pragma unroll
      for (int q=0;q<4;q++){
        unsigned pk = (unsigned)f2bf(a[q]) | ((unsigned)f2bf(c[q])<<16);
        *(unsigned*)&At[(nh*32 + j*4 + q)*264 + c0] = pk;
      }
    }
  }
  __syncthreads();

  bf16x8 afr[8];
#pragma unroll
  for (int kc=0;kc<8;kc++)
    afr[kc] = *(const bf16x8*)&At[(w*16+l15)*264 + kc*32 + kg*8];

  for (int och = 0; och < 12; och++){
    {
      int o8 = tid>>3, cp8 = tid&7;
      const u16* wsrc = Wcat + ((size_t)(och*32 + o8))*256 + cp8*8;
#pragma unroll
      for (int j=0;j<4;j++)
        *(u16x8*)&Wt_[o8*264 + cp8*8 + j*64] = *(const u16x8*)(wsrc + j*64);
    }
    __syncthreads();

    f32x4 acc0 = f4zero(), acc1 = f4zero();
#pragma unroll
    for (int kc=0;kc<8;kc++){
      bf16x8 b0 = *(const bf16x8*)&Wt_[(l15)*264 + kc*32 + kg*8];
      bf16x8 b1 = *(const bf16x8*)&Wt_[(16+l15)*264 + kc*32 + kg*8];
      acc0 = mfma16(afr[kc], b0, acc0);
      acc1 = mfma16(afr[kc], b1, acc1);
    }

    if (och < 8){
      u16* dst = (och < 4) ? theta : kproj;
      int oo = (och & 3) * 32;
#pragma unroll
      for (int of=0;of<2;of++){
        int o = oo + of*16 + l15;
        float bias = biasc[och*32 + of*16 + l15];
        f32x4 acc = of ? acc1 : acc0;
#pragma unroll
        for (int i=0;i<4;i++){
          int n = nb + w*16 + kg*4 + i;
          dst[((size_t)b*N_ + n)*CI_ + o] = f2bf(acc[i] + bias);
        }
      }
      __syncthreads();
    } else {
#pragma unroll
      for (int of=0;of<2;of++){
        int o = of*16 + l15;
        float bias = biasc[och*32 + of*16 + l15];
        f32x4 acc = of ? acc1 : acc0;
#pragma unroll
        for (int i=0;i<4;i++){
          int r = w*16 + kg*4 + i;
          gbuf[o*72 + r] = f2bf(acc[i] + bias);
        }
      }
      __syncthreads();
      {
        int o = tid>>3, np = tid&7;
        int og = (och-8)*32 + o;
        u16x8 v = *(const u16x8*)&gbuf[o*72 + np*8];
        *(u16x8*)(gT + ((size_t)b*CI_ + og)*N_ + nb + np*8) = v;
      }
      __syncthreads();
    }
  }
}

// ---------------- K2: flash attention, swapped 32x32 MFMA, CH=4 KV-split ----------------
// Grid 256 blocks x 512 threads (8 waves x 32 q-rows). bid&7 = (b,chunk) -> XCD.
// Kt [64 k][128 c] XOR-swizzled; Vt [128 c][64 k] XOR-swizzled; dbuf; reg-staged write-late.
__global__ __launch_bounds__(512, 2) void k2_attn(const u16* __restrict__ theta,
      const u16* __restrict__ kproj, const u16* __restrict__ gT,
      u16* __restrict__ pO, float* __restrict__ pM, float* __restrict__ pL){
  constexpr int CHUNK_N = 2048;
  constexpr int NTI = CHUNK_N / KVB;   // 32
  __shared__ char smem[65536];   // [0,32K): Kt dbuf, [32K,64K): Vt dbuf
  char* kbase = smem;
  char* vbase = smem + 32768;
  int tid = threadIdx.x;
  int bid = blockIdx.x;
  int combo = bid & 7;
  int b = combo & 1;
  int chunk = combo >> 1;
  int qblk = bid >> 3;                 // 0..31
  int n0 = chunk * CHUNK_N;
  int w = tid >> 6, lane = tid & 63;
  int l31 = lane & 31, hi = lane >> 5;
  int qg = qblk*256 + w*32 + l31;

  // Q into registers: lane holds its hi-half of row qg (64 of 128 channels)
  bf16x8 qf[8];
  {
    const u16* qsrc = theta + ((size_t)b*N_ + qg)*CI_ + hi*8;
#pragma unroll
    for (int cc=0; cc<8; cc++) qf[cc] = *(const bf16x8*)(qsrc + cc*16);
  }

  // staging assignment (512 threads, 32 B each per tile per array)
  int krow_s = tid >> 3, kpart = tid & 7;
  int vrow_s = tid >> 2, vpart = tid & 3;
  const u16* ksrc = kproj + ((size_t)b*N_ + n0 + krow_s)*CI_ + kpart*16;
  const u16* vsrc = gT + ((size_t)b*CI_ + vrow_s)*N_ + n0 + vpart*16;
  int kw_off[2], vw_off[2];
#pragma unroll
  for (int j=0;j<2;j++){
    int cb = kpart*32 + j*16;
    kw_off[j] = krow_s*256 + (cb ^ ((krow_s&7)<<4));
    int kb = vpart*32 + j*16;
    vw_off[j] = vrow_s*128 + (kb ^ ((vrow_s&7)<<4));
  }
  // precomputed read offsets (within one buffer)
  int swz = (l31&7)<<4;
  int kro[8], vro[4];
#pragma unroll
  for (int cc=0;cc<8;cc++) kro[cc] = l31*256 + ((cc*32 + hi*16) ^ swz);
#pragma unroll
  for (int ks=0;ks<4;ks++) vro[ks] = l31*128 + ((ks*32 + hi*16) ^ swz);

  // prologue: stage tile 0 into buf0
#pragma unroll
  for (int j=0;j<2;j++){
    *(u16x8*)(kbase + kw_off[j]) = *(const u16x8*)(ksrc + j*8);
    *(u16x8*)(vbase + vw_off[j]) = *(const u16x8*)(vsrc + j*8);
  }
  __syncthreads();

  f32x16 oacc[4];
#pragma unroll
  for (int i=0;i<4;i++) oacc[i] = f16zero();
  float mrun = -1e30f, lrun = 0.f;

  for (int t=0; t<NTI; t++){
    int cur = t & 1;
    char* kb_c = kbase + cur*16384;
    char* vb_c = vbase + cur*16384;
    u16x8 kst[2], vst[2];
    bool pf = (t+1 < NTI);
    if (pf){
      const u16* ks = ksrc + (size_t)(t+1)*KVB*CI_;
      const u16* vs = vsrc + (t+1)*KVB;
#pragma unroll
      for (int j=0;j<2;j++) kst[j] = *(const u16x8*)(ks + j*8);
#pragma unroll
      for (int j=0;j<2;j++) vst[j] = *(const u16x8*)(vs + j*8);
    }

    // --- QK^T (swapped): sA = S^T rows k 0..31, sB rows k 32..63; col = q = l31
    f32x16 sA = f16zero(), sB = f16zero();
    __builtin_amdgcn_s_setprio(1);
#pragma unroll
    for (int cc=0; cc<8; cc++){
      bf16x8 kf0 = *(const bf16x8*)(kb_c + kro[cc]);
      bf16x8 kf1 = *(const bf16x8*)(kb_c + 8192 + kro[cc]);
      sA = mfma32(kf0, qf[cc], sA);
      sB = mfma32(kf1, qf[cc], sB);
    }
    __builtin_amdgcn_s_setprio(0);

    // --- online softmax (exp2 domain), fully in-register
    float t8[8];
#pragma unroll
    for (int i=0;i<8;i++) t8[i] = fmaxf(fmaxf(sA[i], sA[i+8]), fmaxf(sB[i], sB[i+8]));
    float m4a = fmaxf(t8[0], t8[4]), m4b = fmaxf(t8[1], t8[5]);
    float m4c = fmaxf(t8[2], t8[6]), m4d = fmaxf(t8[3], t8[7]);
    float mx = fmaxf(fmaxf(m4a, m4b), fmaxf(m4c, m4d));
    mx = fmaxf(mx, __shfl_xor(mx, 32));
    if (__any(mx > mrun + 12.f)){       // T13 defer-max (12 in log2 units)
      float mnew = fmaxf(mrun, mx);
      float sc = exp2f(mrun - mnew);
      lrun *= sc;
#pragma unroll
      for (int i=0;i<4;i++)
#pragma unroll
        for (int r=0;r<16;r++) oacc[i][r] *= sc;
      mrun = mnew;
    }
    float pA[16], pB[16];
#pragma unroll
    for (int r=0;r<16;r++){ pA[r] = exp2f(sA[r]-mrun); pB[r] = exp2f(sB[r]-mrun); }
    float s8[8];
#pragma unroll
    for (int i=0;i<8;i++) s8[i] = (pA[i]+pA[i+8]) + (pB[i]+pB[i+8]);
    float s4a = s8[0]+s8[4], s4b = s8[1]+s8[5], s4c = s8[2]+s8[6], s4d = s8[3]+s8[7];
    float ps = (s4a+s4b) + (s4c+s4d);
    ps += __shfl_xor(ps, 32);
    lrun += ps;

    // --- T14 write-late: staged regs -> other buffer (overlaps with PV)
    if (pf){
      char* kd = kbase + (cur^1)*16384;
      char* vd = vbase + (cur^1)*16384;
#pragma unroll
      for (int j=0;j<2;j++) *(u16x8*)(kd + kw_off[j]) = kst[j];
#pragma unroll
      for (int j=0;j<2;j++) *(u16x8*)(vd + vw_off[j]) = vst[j];
    }

    // --- PV (swapped): oacc[c2] = O^T chunk rows c, col q = l31
    __builtin_amdgcn_s_setprio(1);
#pragma unroll
    for (int ks=0; ks<4; ks++){
      const float* P = (ks<2) ? pA : pB;
      int r0 = (ks&1)*8;
      unsigned a0 = cvtpk(P[r0+0], P[r0+1]);
      unsigned b0 = cvtpk(P[r0+4], P[r0+5]);
      unsigned a1 = cvtpk(P[r0+2], P[r0+3]);
      unsigned b1 = cvtpk(P[r0+6], P[r0+7]);
      plswap(a0, b0); plswap(a1, b1);
      union { unsigned u[4]; bf16x8 v; } pb;
      pb.u[0]=a0; pb.u[1]=a1; pb.u[2]=b0; pb.u[3]=b1;
#pragma unroll
      for (int c2=0; c2<4; c2++){
        bf16x8 vf = *(const bf16x8*)(vb_c + c2*4096 + vro[ks]);
        oacc[c2] = mfma32(vf, pb.v, oacc[c2]);
      }
    }
    __builtin_amdgcn_s_setprio(0);
    __syncthreads();
  }

  // --- epilogue: O^T -> per-wave LDS region (bf16, swizzled) -> coalesced partial store
  char* region = smem + w*8192;   // 8 waves x 8 KB (reuses K/V buffers)
#pragma unroll
  for (int c2=0;c2<4;c2++)
#pragma unroll
    for (int r=0;r<16;r++){
      int c = c2*32 + (r&3) + 8*(r>>2) + 4*hi;
      *(u16*)(region + l31*256 + ((c*2) ^ swz)) = f2bf(oacc[c2][r]);
    }
  __syncthreads();
  {
    int ql = lane >> 1, half = lane & 1;
    int qg2 = qblk*256 + w*32 + ql;
    u16* dst = pO + ((size_t)(chunk*2 + b)*N_ + qg2)*CI_ + half*64;
    int rswz = (ql&7)<<4;
#pragma unroll
    for (int j=0;j<8;j++){
      u16x8 v2 = *(const u16x8*)(region + ql*256 + ((half*128 + j*16) ^ rswz));
      *(u16x8*)(dst + j*8) = v2;
    }
  }
  if (hi == 0){
    pM[(size_t)(chunk*2 + b)*N_ + qg] = mrun;
    pL[(size_t)(chunk*2 + b)*N_ + qg] = lrun;
  }
}

// ---------------- K3: fused combine(pO chunks) + wy = Ww @ y + bw + stats ----------------
__global__ __launch_bounds__(256) void k3_wy(const u16* __restrict__ pO,
    const float* __restrict__ pM, const float* __restrict__ pL,
    const u16* __restrict__ Wwb, const float* __restrict__ bw,
    u16* __restrict__ wy, float* __restrict__ stats){
  __shared__ u16 Yt[64*136];
  __shared__ u16 Wt_[64*136];
  __shared__ float wyb[64*72];
  int tid = threadIdx.x;
  int b  = blockIdx.x >> 7;
  int nb = (blockIdx.x & 127) * 64;
  int w = tid>>6, lane = tid&63;
  int l15 = lane&15, kg = lane>>4;

  // stage y tile [64 n][128 c]: combine 4 KV-chunk partials -> bf16
  {
    int n = tid>>2, cp = tid&3;
    size_t q = (size_t)nb + n;
    float m[4], l[4];
#pragma unroll
    for (int ch=0; ch<4; ch++){
      m[ch] = pM[(size_t)(ch*2+b)*N_ + q];
      l[ch] = pL[(size_t)(ch*2+b)*N_ + q];
    }
    float M = fmaxf(fmaxf(m[0],m[1]), fmaxf(m[2],m[3]));
    float wts[4]; float L = 0.f;
#pragma unroll
    for (int ch=0; ch<4; ch++){ wts[ch] = exp2f(m[ch]-M); L += wts[ch]*l[ch]; }
    float inv = 1.f/L;
#pragma unroll
    for (int j=0;j<4;j++){
      int c0 = cp*32 + j*8;
      float acc[8];
#pragma unroll
      for (int i=0;i<8;i++) acc[i]=0.f;
#pragma unroll
      for (int ch=0; ch<4; ch++){
        u16x8 v = *(const u16x8*)(pO + ((size_t)(ch*2+b)*N_ + q)*CI_ + c0);
#pragma unroll
        for (int i=0;i<8;i++) acc[i] += wts[ch]*bf2f(v[i]);
      }
#pragma unroll
      for (int i=0;i<4;i++){
        unsigned pk = (unsigned)f2bf(acc[2*i]*inv) | ((unsigned)f2bf(acc[2*i+1]*inv)<<16);
        *(unsigned*)&Yt[n*136 + c0 + 2*i] = pk;
      }
    }
  }
  __syncthreads();

  bf16x8 afr[4];
#pragma unroll
  for (int kc=0;kc<4;kc++)
    afr[kc] = *(const bf16x8*)&Yt[(w*16+l15)*136 + kc*32 + kg*8];

  for (int oc=0; oc<4; oc++){
    {
      int o = tid>>2, cp = tid&3;
      const u16* src = Wwb + ((size_t)(oc*64 + o))*CI_ + cp*32;
#pragma unroll
      for (int j=0;j<4;j++)
        *(u16x8*)&Wt_[o*136 + cp*32 + j*8] = *(const u16x8*)(src + j*8);
    }
    __syncthreads();

    f32x4 acc[4];
#pragma unroll
    for (int of=0;of<4;of++) acc[of] = f4zero();
#pragma unroll
    for (int kc=0;kc<4;kc++){
#pragma unroll
      for (int of=0;of<4;of++){
        bf16x8 bfr = *(const bf16x8*)&Wt_[(of*16+l15)*136 + kc*32 + kg*8];
        acc[of] = mfma16(afr[kc], bfr, acc[of]);
      }
    }
#pragma unroll
    for (int of=0;of<4;of++){
#pragma unroll
      for (int i=0;i<4;i++)
        wyb[(of*16+l15)*72 + w*16 + kg*4 + i] = acc[of][i];
    }
    __syncthreads();
    {
      int o = tid>>2, np = tid&3;
      int og = oc*64 + o;
      float bias = bw[og];
      float sm = 0.f, sq = 0.f;
      u16* dst = wy + ((size_t)b*C_ + og)*N_ + nb + np*16;
      u16 buf[16];
#pragma unroll
      for (int j=0;j<4;j++){
#pragma unroll
        for (int q2=0;q2<4;q2++){
          float t2 = wyb[o*72 + np*16 + j*4 + q2] + bias;
          buf[j*4+q2] = f2bf(t2); sm += t2; sq += t2*t2;
        }
      }
      *(u16x8*)dst = *(const u16x8*)&buf[0];
      *(u16x8*)(dst+8) = *(const u16x8*)&buf[8];
      sm += __shfl_xor(sm, 1); sm += __shfl_xor(sm, 2);
      sq += __shfl_xor(sq, 1); sq += __shfl_xor(sq, 2);
      if ((tid&3)==0){
        atomicAdd(&stats[og], sm);
        atomicAdd(&stats[256+og], sq);
      }
    }
    __syncthreads();
  }
}

// ---------------- K4: BN (batch stats) + residual ----------------
__global__ __launch_bounds__(256) void k4_bn(const u16* __restrict__ wy,
    const float* __restrict__ x, const float* __restrict__ stats,
    const float* __restrict__ gamma, const float* __restrict__ beta,
    float* __restrict__ out){
  size_t base = ((size_t)blockIdx.x)*2048 + (size_t)threadIdx.x*8;
  int o = (int)((base >> 13) & 255);
  const float invn = 1.f/16384.f;
  float mean = stats[o]*invn;
  float var  = stats[256+o]*invn - mean*mean;
  float rs = rsqrtf(var + 1e-5f);
  float g = gamma[o]*rs;
  float bb = beta[o];
  u16x8 a = *(const u16x8*)(wy + base);
  f32x4 x0 = *(const f32x4*)(x + base);
  f32x4 x1 = *(const f32x4*)(x + base + 4);
  f32x4 r0, r1;
#pragma unroll
  for (int q=0;q<4;q++){
    r0[q] = (bf2f(a[q])-mean)*g + bb + x0[q];
    r1[q] = (bf2f(a[4+q])-mean)*g + bb + x1[q];
  }
  *(f32x4*)(out + base)     = r0;
  *(f32x4*)(out + base + 4) = r1;
}

extern "C" void kernel_launch(void* const* d_in, const int* in_sizes, int n_in,
                              void* d_out, int out_size, void* d_ws, size_t ws_size,
                              hipStream_t stream){
  const float* x     = (const float*)d_in[0];
  const float* Wt    = (const float*)d_in[1];
  const float* bt    = (const float*)d_in[2];
  const float* Wp    = (const float*)d_in[3];
  const float* bp    = (const float*)d_in[4];
  const float* Wg    = (const float*)d_in[5];
  const float* bg    = (const float*)d_in[6];
  const float* Ww    = (const float*)d_in[7];
  const float* bw    = (const float*)d_in[8];
  const float* gamma = (const float*)d_in[9];
  const float* beta  = (const float*)d_in[10];

  char* ws = (char*)d_ws;
  // [0,4M) theta | [4M,8M) kproj | [8M,12M) gT           (bf16)
  // [12M, +16M) pO bf16 [4ch][2b][8192][128]
  // then pM (256K), pL (256K), wy bf16 (8M), Wcat, Wwb, biasc, stats  (~36.8 MiB total)
  u16*   theta = (u16*)(ws + 0);
  u16*   kproj = (u16*)(ws + 4194304);
  u16*   gT    = (u16*)(ws + 8388608);
  u16*   pO    = (u16*)(ws + 12582912);
  float* pM    = (float*)(ws + 29360128);
  float* pL    = (float*)(ws + 29622272);
  u16*   wy    = (u16*)(ws + 29884416);
  u16*   Wcat  = (u16*)(ws + 38273024);
  u16*   Wwb   = (u16*)(ws + 38469632);
  float* biasc = (float*)(ws + 38535168);
  float* stats = (float*)(ws + 38536704);
  float* out   = (float*)d_out;

  k0_prep<<<64, 256, 0, stream>>>(Wt, Wp, Wg, Ww, bt, bp, bg, Wcat, Wwb, biasc, stats);
  k1_proj<<<256, 256, 0, stream>>>(x, Wcat, biasc, theta, kproj, gT);
  k2_attn<<<256, 512, 0, stream>>>(theta, kproj, gT, pO, pM, pL);
  k3_wy<<<256, 256, 0, stream>>>(pO, pM, pL, Wwb, bw, wy, stats);
  k4_bn<<<2048, 256, 0, stream>>>(wy, x, stats, gamma, beta, out);
}

// Round 8
// 131.852 us; speedup vs baseline: 2.2829x; 1.0794x over previous
//
#include <hip/hip_runtime.h>
#include <cstdint>
#include <cstddef>

// NonLocalBlock3D: B=2, C=256, Ci=128, N=D*H*W=8192.
// k0 prep -> k1 projections -> k2 flash attention (CH=4 KV-split, 512-thr blocks,
// reg-staged write-late dbuf) -> k3 combine+wy GEMM+stats -> k4 BN+res.
// Softmax in exp2 domain (log2e folded into Wt/bt), raw v_exp_f32.
// R3: never cap k2 VGPR via launch_bounds min-waves (spills 600 MB scratch). (512,2) safe.
// R4: 8-wave blocks can't double up (unified regs ~160/wave); ceiling 8 waves/CU here.
// R5: 128-q blocks double staging traffic -> VALU-bound. Keep 256-q blocks.
// R6: global_load_lds staging REGRESSED (compiler serializes DMA vs ds_read). Keep reg-staged.
// R7: libm exp2f lowers to OCML slow path (~8 VALU ops); use __builtin_amdgcn_exp2f (1 op).
//     K-tile swizzle extended to (row&15)<<4: 256B rows have 16 slots; period-8 left 4-way
//     aliasing across the 32 rows a wave reads -> now 2-way (free).

typedef unsigned short u16;
typedef __bf16 bf16x8 __attribute__((ext_vector_type(8)));
typedef float f32x4 __attribute__((ext_vector_type(4)));
typedef float f32x16 __attribute__((ext_vector_type(16)));
typedef unsigned short u16x8 __attribute__((ext_vector_type(8)));

#define B_ 2
#define C_ 256
#define CI_ 128
#define N_ 8192
#define KVB 64

static __device__ __forceinline__ u16 f2bf(float f){
  unsigned u = __builtin_bit_cast(unsigned, f);
  unsigned r = (u + 0x7FFFu + ((u>>16)&1u)) >> 16;
  return (u16)r;
}
static __device__ __forceinline__ float bf2f(u16 v){
  unsigned u = ((unsigned)v) << 16;
  return __builtin_bit_cast(float, u);
}
static __device__ __forceinline__ float fexp2(float x){
  return __builtin_amdgcn_exp2f(x);     // raw v_exp_f32, no OCML denormal fixup
}
static __device__ __forceinline__ f32x4 f4zero(){
  f32x4 v; v[0]=0.f; v[1]=0.f; v[2]=0.f; v[3]=0.f; return v;
}
static __device__ __forceinline__ f32x16 f16zero(){
  f32x16 v;
#pragma unroll
  for (int i=0;i<16;i++) v[i]=0.f;
  return v;
}
static __device__ __forceinline__ f32x4 mfma16(bf16x8 a, bf16x8 b, f32x4 c){
  return __builtin_amdgcn_mfma_f32_16x16x32_bf16(a, b, c, 0, 0, 0);
}
static __device__ __forceinline__ f32x16 mfma32(bf16x8 a, bf16x8 b, f32x16 c){
  return __builtin_amdgcn_mfma_f32_32x32x16_bf16(a, b, c, 0, 0, 0);
}
static __device__ __forceinline__ unsigned cvtpk(float lo, float hi){
  unsigned r;
  asm("v_cvt_pk_bf16_f32 %0, %1, %2" : "=v"(r) : "v"(lo), "v"(hi));
  return r;
}
static __device__ __forceinline__ void plswap(unsigned &a, unsigned &b){
  asm volatile("v_permlane32_swap_b32 %0, %1" : "+v"(a), "+v"(b));
}

#define LOG2E 1.4426950408889634f

// ---------------- K0: weight pack (fp32 -> bf16), bias concat, zero stats ----------------
__global__ void k0_prep(const float* __restrict__ Wt, const float* __restrict__ Wp,
                        const float* __restrict__ Wg, const float* __restrict__ Ww,
                        const float* __restrict__ bt, const float* __restrict__ bp,
                        const float* __restrict__ bg,
                        u16* __restrict__ Wcat, u16* __restrict__ Wwb,
                        float* __restrict__ biasc, float* __restrict__ stats){
  int t = blockIdx.x*blockDim.x + threadIdx.x;
  int nthr = gridDim.x*blockDim.x;
  for (int i = t; i < 32768; i += nthr){
    Wcat[i]        = f2bf(Wt[i] * LOG2E);
    Wcat[32768+i]  = f2bf(Wp[i]);
    Wcat[65536+i]  = f2bf(Wg[i]);
    Wwb[i]         = f2bf(Ww[i]);
  }
  for (int i = t; i < 128; i += nthr){
    biasc[i] = bt[i] * LOG2E; biasc[128+i] = bp[i]; biasc[256+i] = bg[i];
  }
  for (int i = t; i < 512; i += nthr) stats[i] = 0.f;
}

// ---------------- K1: fused transpose + 3 projections ----------------
__global__ __launch_bounds__(256) void k1_proj(const float* __restrict__ x,
     const u16* __restrict__ Wcat, const float* __restrict__ biasc,
     u16* __restrict__ theta, u16* __restrict__ kproj, u16* __restrict__ gT){
  __shared__ u16 At[64*264];
  __shared__ u16 Wt_[32*264];
  __shared__ u16 gbuf[32*72];
  int tid = threadIdx.x;
  int b  = blockIdx.x >> 7;
  int nb = (blockIdx.x & 127) * 64;
  int w = tid >> 6, lane = tid & 63;
  int l15 = lane & 15, kg = lane >> 4;

  {
    int cp = tid & 127, nh = tid >> 7;
    int c0 = cp*2;
    const float* src0 = x + ((size_t)(b*C_ + c0))*N_ + nb + nh*32;
    const float* src1 = src0 + N_;
#pragma unroll
    for (int j=0;j<8;j++){
      f32x4 a = *(const f32x4*)(src0 + j*4);
      f32x4 c = *(const f32x4*)(src1 + j*4);
#pragma unroll
      for (int q=0;q<4;q++){
        unsigned pk = (unsigned)f2bf(a[q]) | ((unsigned)f2bf(c[q])<<16);
        *(unsigned*)&At[(nh*32 + j*4 + q)*264 + c0] = pk;
      }
    }
  }
  __syncthreads();

  bf16x8 afr[8];
#pragma unroll
  for (int kc=0;kc<8;kc++)
    afr[kc] = *(const bf16x8*)&At[(w*16+l15)*264 + kc*32 + kg*8];

  for (int och = 0; och < 12; och++){
    {
      int o8 = tid>>3, cp8 = tid&7;
      const u16* wsrc = Wcat + ((size_t)(och*32 + o8))*256 + cp8*8;
#pragma unroll
      for (int j=0;j<4;j++)
        *(u16x8*)&Wt_[o8*264 + cp8*8 + j*64] = *(const u16x8*)(wsrc + j*64);
    }
    __syncthreads();

    f32x4 acc0 = f4zero(), acc1 = f4zero();
#pragma unroll
    for (int kc=0;kc<8;kc++){
      bf16x8 b0 = *(const bf16x8*)&Wt_[(l15)*264 + kc*32 + kg*8];
      bf16x8 b1 = *(const bf16x8*)&Wt_[(16+l15)*264 + kc*32 + kg*8];
      acc0 = mfma16(afr[kc], b0, acc0);
      acc1 = mfma16(afr[kc], b1, acc1);
    }

    if (och < 8){
      u16* dst = (och < 4) ? theta : kproj;
      int oo = (och & 3) * 32;
#pragma unroll
      for (int of=0;of<2;of++){
        int o = oo + of*16 + l15;
        float bias = biasc[och*32 + of*16 + l15];
        f32x4 acc = of ? acc1 : acc0;
#pragma unroll
        for (int i=0;i<4;i++){
          int n = nb + w*16 + kg*4 + i;
          dst[((size_t)b*N_ + n)*CI_ + o] = f2bf(acc[i] + bias);
        }
      }
      __syncthreads();
    } else {
#pragma unroll
      for (int of=0;of<2;of++){
        int o = of*16 + l15;
        float bias = biasc[och*32 + of*16 + l15];
        f32x4 acc = of ? acc1 : acc0;
#pragma unroll
        for (int i=0;i<4;i++){
          int r = w*16 + kg*4 + i;
          gbuf[o*72 + r] = f2bf(acc[i] + bias);
        }
      }
      __syncthreads();
      {
        int o = tid>>3, np = tid&7;
        int og = (och-8)*32 + o;
        u16x8 v = *(const u16x8*)&gbuf[o*72 + np*8];
        *(u16x8*)(gT + ((size_t)b*CI_ + og)*N_ + nb + np*8) = v;
      }
      __syncthreads();
    }
  }
}

// ---------------- K2: flash attention, swapped 32x32 MFMA, CH=4 KV-split ----------------
// Grid 256 blocks x 512 threads (8 waves x 32 q-rows). bid&7 = (b,chunk) -> XCD.
// Kt [64 k][128 c] XOR-swizzled (row&15); Vt [128 c][64 k] XOR-swizzled (row&7);
// dbuf; reg-staged write-late.
__global__ __launch_bounds__(512, 2) void k2_attn(const u16* __restrict__ theta,
      const u16* __restrict__ kproj, const u16* __restrict__ gT,
      u16* __restrict__ pO, float* __restrict__ pM, float* __restrict__ pL){
  constexpr int CHUNK_N = 2048;
  constexpr int NTI = CHUNK_N / KVB;   // 32
  __shared__ char smem[65536];   // [0,32K): Kt dbuf, [32K,64K): Vt dbuf
  char* kbase = smem;
  char* vbase = smem + 32768;
  int tid = threadIdx.x;
  int bid = blockIdx.x;
  int combo = bid & 7;
  int b = combo & 1;
  int chunk = combo >> 1;
  int qblk = bid >> 3;                 // 0..31
  int n0 = chunk * CHUNK_N;
  int w = tid >> 6, lane = tid & 63;
  int l31 = lane & 31, hi = lane >> 5;
  int qg = qblk*256 + w*32 + l31;

  // Q into registers: lane holds its hi-half of row qg (64 of 128 channels)
  bf16x8 qf[8];
  {
    const u16* qsrc = theta + ((size_t)b*N_ + qg)*CI_ + hi*8;
#pragma unroll
    for (int cc=0; cc<8; cc++) qf[cc] = *(const bf16x8*)(qsrc + cc*16);
  }

  // staging assignment (512 threads, 32 B each per tile per array)
  int krow_s = tid >> 3, kpart = tid & 7;
  int vrow_s = tid >> 2, vpart = tid & 3;
  const u16* ksrc = kproj + ((size_t)b*N_ + n0 + krow_s)*CI_ + kpart*16;
  const u16* vsrc = gT + ((size_t)b*CI_ + vrow_s)*N_ + n0 + vpart*16;
  int kw_off[2], vw_off[2];
#pragma unroll
  for (int j=0;j<2;j++){
    int cb = kpart*32 + j*16;
    kw_off[j] = krow_s*256 + (cb ^ ((krow_s&15)<<4));
    int kb = vpart*32 + j*16;
    vw_off[j] = vrow_s*128 + (kb ^ ((vrow_s&7)<<4));
  }
  // precomputed read offsets (within one buffer)
  int kswz = (l31&15)<<4;              // K rows: (32+l31)&15 == l31&15, one offset serves both halves
  int vswz = (l31&7)<<4;
  int kro[8], vro[4];
#pragma unroll
  for (int cc=0;cc<8;cc++) kro[cc] = l31*256 + ((cc*32 + hi*16) ^ kswz);
#pragma unroll
  for (int ks=0;ks<4;ks++) vro[ks] = l31*128 + ((ks*32 + hi*16) ^ vswz);

  // prologue: stage tile 0 into buf0
#pragma unroll
  for (int j=0;j<2;j++){
    *(u16x8*)(kbase + kw_off[j]) = *(const u16x8*)(ksrc + j*8);
    *(u16x8*)(vbase + vw_off[j]) = *(const u16x8*)(vsrc + j*8);
  }
  __syncthreads();

  f32x16 oacc[4];
#pragma unroll
  for (int i=0;i<4;i++) oacc[i] = f16zero();
  float mrun = -1e30f, lrun = 0.f;

  for (int t=0; t<NTI; t++){
    int cur = t & 1;
    char* kb_c = kbase + cur*16384;
    char* vb_c = vbase + cur*16384;
    u16x8 kst[2], vst[2];
    bool pf = (t+1 < NTI);
    if (pf){
      const u16* ks = ksrc + (size_t)(t+1)*KVB*CI_;
      const u16* vs = vsrc + (t+1)*KVB;
#pragma unroll
      for (int j=0;j<2;j++) kst[j] = *(const u16x8*)(ks + j*8);
#pragma unroll
      for (int j=0;j<2;j++) vst[j] = *(const u16x8*)(vs + j*8);
    }

    // --- QK^T (swapped): sA = S^T rows k 0..31, sB rows k 32..63; col = q = l31
    f32x16 sA = f16zero(), sB = f16zero();
    __builtin_amdgcn_s_setprio(1);
#pragma unroll
    for (int cc=0; cc<8; cc++){
      bf16x8 kf0 = *(const bf16x8*)(kb_c + kro[cc]);
      bf16x8 kf1 = *(const bf16x8*)(kb_c + 8192 + kro[cc]);
      sA = mfma32(kf0, qf[cc], sA);
      sB = mfma32(kf1, qf[cc], sB);
    }
    __builtin_amdgcn_s_setprio(0);

    // --- online softmax (exp2 domain), fully in-register
    float t8[8];
#pragma unroll
    for (int i=0;i<8;i++) t8[i] = fmaxf(fmaxf(sA[i], sA[i+8]), fmaxf(sB[i], sB[i+8]));
    float m4a = fmaxf(t8[0], t8[4]), m4b = fmaxf(t8[1], t8[5]);
    float m4c = fmaxf(t8[2], t8[6]), m4d = fmaxf(t8[3], t8[7]);
    float mx = fmaxf(fmaxf(m4a, m4b), fmaxf(m4c, m4d));
    mx = fmaxf(mx, __shfl_xor(mx, 32));
    if (__any(mx > mrun + 12.f)){       // T13 defer-max (12 in log2 units)
      float mnew = fmaxf(mrun, mx);
      float sc = fexp2(mrun - mnew);
      lrun *= sc;
#pragma unroll
      for (int i=0;i<4;i++)
#pragma unroll
        for (int r=0;r<16;r++) oacc[i][r] *= sc;
      mrun = mnew;
    }
    float pA[16], pB[16];
#pragma unroll
    for (int r=0;r<16;r++){ pA[r] = fexp2(sA[r]-mrun); pB[r] = fexp2(sB[r]-mrun); }
    float s8[8];
#pragma unroll
    for (int i=0;i<8;i++) s8[i] = (pA[i]+pA[i+8]) + (pB[i]+pB[i+8]);
    float s4a = s8[0]+s8[4], s4b = s8[1]+s8[5], s4c = s8[2]+s8[6], s4d = s8[3]+s8[7];
    float ps = (s4a+s4b) + (s4c+s4d);
    ps += __shfl_xor(ps, 32);
    lrun += ps;

    // --- T14 write-late: staged regs -> other buffer (overlaps with PV)
    if (pf){
      char* kd = kbase + (cur^1)*16384;
      char* vd = vbase + (cur^1)*16384;
#pragma unroll
      for (int j=0;j<2;j++) *(u16x8*)(kd + kw_off[j]) = kst[j];
#pragma unroll
      for (int j=0;j<2;j++) *(u16x8*)(vd + vw_off[j]) = vst[j];
    }

    // --- PV (swapped): oacc[c2] = O^T chunk rows c, col q = l31
    __builtin_amdgcn_s_setprio(1);
#pragma unroll
    for (int ks=0; ks<4; ks++){
      const float* P = (ks<2) ? pA : pB;
      int r0 = (ks&1)*8;
      unsigned a0 = cvtpk(P[r0+0], P[r0+1]);
      unsigned b0 = cvtpk(P[r0+4], P[r0+5]);
      unsigned a1 = cvtpk(P[r0+2], P[r0+3]);
      unsigned b1 = cvtpk(P[r0+6], P[r0+7]);
      plswap(a0, b0); plswap(a1, b1);
      union { unsigned u[4]; bf16x8 v; } pb;
      pb.u[0]=a0; pb.u[1]=a1; pb.u[2]=b0; pb.u[3]=b1;
#pragma unroll
      for (int c2=0; c2<4; c2++){
        bf16x8 vf = *(const bf16x8*)(vb_c + c2*4096 + vro[ks]);
        oacc[c2] = mfma32(vf, pb.v, oacc[c2]);
      }
    }
    __builtin_amdgcn_s_setprio(0);
    __syncthreads();
  }

  // --- epilogue: O^T -> per-wave LDS region (bf16, swizzled) -> coalesced partial store
  char* region = smem + w*8192;   // 8 waves x 8 KB (reuses K/V buffers)
#pragma unroll
  for (int c2=0;c2<4;c2++)
#pragma unroll
    for (int r=0;r<16;r++){
      int c = c2*32 + (r&3) + 8*(r>>2) + 4*hi;
      *(u16*)(region + l31*256 + ((c*2) ^ vswz)) = f2bf(oacc[c2][r]);
    }
  __syncthreads();
  {
    int ql = lane >> 1, half = lane & 1;
    int qg2 = qblk*256 + w*32 + ql;
    u16* dst = pO + ((size_t)(chunk*2 + b)*N_ + qg2)*CI_ + half*64;
    int rswz = (ql&7)<<4;
#pragma unroll
    for (int j=0;j<8;j++){
      u16x8 v2 = *(const u16x8*)(region + ql*256 + ((half*128 + j*16) ^ rswz));
      *(u16x8*)(dst + j*8) = v2;
    }
  }
  if (hi == 0){
    pM[(size_t)(chunk*2 + b)*N_ + qg] = mrun;
    pL[(size_t)(chunk*2 + b)*N_ + qg] = lrun;
  }
}

// ---------------- K3: fused combine(pO chunks) + wy = Ww @ y + bw + stats ----------------
__global__ __launch_bounds__(256) void k3_wy(const u16* __restrict__ pO,
    const float* __restrict__ pM, const float* __restrict__ pL,
    const u16* __restrict__ Wwb, const float* __restrict__ bw,
    u16* __restrict__ wy, float* __restrict__ stats){
  __shared__ u16 Yt[64*136];
  __shared__ u16 Wt_[64*136];
  __shared__ float wyb[64*72];
  int tid = threadIdx.x;
  int b  = blockIdx.x >> 7;
  int nb = (blockIdx.x & 127) * 64;
  int w = tid>>6, lane = tid&63;
  int l15 = lane&15, kg = lane>>4;

  // stage y tile [64 n][128 c]: combine 4 KV-chunk partials -> bf16
  {
    int n = tid>>2, cp = tid&3;
    size_t q = (size_t)nb + n;
    float m[4], l[4];
#pragma unroll
    for (int ch=0; ch<4; ch++){
      m[ch] = pM[(size_t)(ch*2+b)*N_ + q];
      l[ch] = pL[(size_t)(ch*2+b)*N_ + q];
    }
    float M = fmaxf(fmaxf(m[0],m[1]), fmaxf(m[2],m[3]));
    float wts[4]; float L = 0.f;
#pragma unroll
    for (int ch=0; ch<4; ch++){ wts[ch] = exp2f(m[ch]-M); L += wts[ch]*l[ch]; }
    float inv = 1.f/L;
#pragma unroll
    for (int j=0;j<4;j++){
      int c0 = cp*32 + j*8;
      float acc[8];
#pragma unroll
      for (int i=0;i<8;i++) acc[i]=0.f;
#pragma unroll
      for (int ch=0; ch<4; ch++){
        u16x8 v = *(const u16x8*)(pO + ((size_t)(ch*2+b)*N_ + q)*CI_ + c0);
#pragma unroll
        for (int i=0;i<8;i++) acc[i] += wts[ch]*bf2f(v[i]);
      }
#pragma unroll
      for (int i=0;i<4;i++){
        unsigned pk = (unsigned)f2bf(acc[2*i]*inv) | ((unsigned)f2bf(acc[2*i+1]*inv)<<16);
        *(unsigned*)&Yt[n*136 + c0 + 2*i] = pk;
      }
    }
  }
  __syncthreads();

  bf16x8 afr[4];
#pragma unroll
  for (int kc=0;kc<4;kc++)
    afr[kc] = *(const bf16x8*)&Yt[(w*16+l15)*136 + kc*32 + kg*8];

  for (int oc=0; oc<4; oc++){
    {
      int o = tid>>2, cp = tid&3;
      const u16* src = Wwb + ((size_t)(oc*64 + o))*CI_ + cp*32;
#pragma unroll
      for (int j=0;j<4;j++)
        *(u16x8*)&Wt_[o*136 + cp*32 + j*8] = *(const u16x8*)(src + j*8);
    }
    __syncthreads();

    f32x4 acc[4];
#pragma unroll
    for (int of=0;of<4;of++) acc[of] = f4zero();
#pragma unroll
    for (int kc=0;kc<4;kc++){
#pragma unroll
      for (int of=0;of<4;of++){
        bf16x8 bfr = *(const bf16x8*)&Wt_[(of*16+l15)*136 + kc*32 + kg*8];
        acc[of] = mfma16(afr[kc], bfr, acc[of]);
      }
    }
#pragma unroll
    for (int of=0;of<4;of++){
#pragma unroll
      for (int i=0;i<4;i++)
        wyb[(of*16+l15)*72 + w*16 + kg*4 + i] = acc[of][i];
    }
    __syncthreads();
    {
      int o = tid>>2, np = tid&3;
      int og = oc*64 + o;
      float bias = bw[og];
      float sm = 0.f, sq = 0.f;
      u16* dst = wy + ((size_t)b*C_ + og)*N_ + nb + np*16;
      u16 buf[16];
#pragma unroll
      for (int j=0;j<4;j++){
#pragma unroll
        for (int q2=0;q2<4;q2++){
          float t2 = wyb[o*72 + np*16 + j*4 + q2] + bias;
          buf[j*4+q2] = f2bf(t2); sm += t2; sq += t2*t2;
        }
      }
      *(u16x8*)dst = *(const u16x8*)&buf[0];
      *(u16x8*)(dst+8) = *(const u16x8*)&buf[8];
      sm += __shfl_xor(sm, 1); sm += __shfl_xor(sm, 2);
      sq += __shfl_xor(sq, 1); sq += __shfl_xor(sq, 2);
      if ((tid&3)==0){
        atomicAdd(&stats[og], sm);
        atomicAdd(&stats[256+og], sq);
      }
    }
    __syncthreads();
  }
}

// ---------------- K4: BN (batch stats) + residual ----------------
__global__ __launch_bounds__(256) void k4_bn(const u16* __restrict__ wy,
    const float* __restrict__ x, const float* __restrict__ stats,
    const float* __restrict__ gamma, const float* __restrict__ beta,
    float* __restrict__ out){
  size_t base = ((size_t)blockIdx.x)*2048 + (size_t)threadIdx.x*8;
  int o = (int)((base >> 13) & 255);
  const float invn = 1.f/16384.f;
  float mean = stats[o]*invn;
  float var  = stats[256+o]*invn - mean*mean;
  float rs = rsqrtf(var + 1e-5f);
  float g = gamma[o]*rs;
  float bb = beta[o];
  u16x8 a = *(const u16x8*)(wy + base);
  f32x4 x0 = *(const f32x4*)(x + base);
  f32x4 x1 = *(const f32x4*)(x + base + 4);
  f32x4 r0, r1;
#pragma unroll
  for (int q=0;q<4;q++){
    r0[q] = (bf2f(a[q])-mean)*g + bb + x0[q];
    r1[q] = (bf2f(a[4+q])-mean)*g + bb + x1[q];
  }
  *(f32x4*)(out + base)     = r0;
  *(f32x4*)(out + base + 4) = r1;
}

extern "C" void kernel_launch(void* const* d_in, const int* in_sizes, int n_in,
                              void* d_out, int out_size, void* d_ws, size_t ws_size,
                              hipStream_t stream){
  const float* x     = (const float*)d_in[0];
  const float* Wt    = (const float*)d_in[1];
  const float* bt    = (const float*)d_in[2];
  const float* Wp    = (const float*)d_in[3];
  const float* bp    = (const float*)d_in[4];
  const float* Wg    = (const float*)d_in[5];
  const float* bg    = (const float*)d_in[6];
  const float* Ww    = (const float*)d_in[7];
  const float* bw    = (const float*)d_in[8];
  const float* gamma = (const float*)d_in[9];
  const float* beta  = (const float*)d_in[10];

  char* ws = (char*)d_ws;
  // [0,4M) theta | [4M,8M) kproj | [8M,12M) gT           (bf16)
  // [12M, +16M) pO bf16 [4ch][2b][8192][128]
  // then pM (256K), pL (256K), wy bf16 (8M), Wcat, Wwb, biasc, stats  (~36.8 MiB total)
  u16*   theta = (u16*)(ws + 0);
  u16*   kproj = (u16*)(ws + 4194304);
  u16*   gT    = (u16*)(ws + 8388608);
  u16*   pO    = (u16*)(ws + 12582912);
  float* pM    = (float*)(ws + 29360128);
  float* pL    = (float*)(ws + 29622272);
  u16*   wy    = (u16*)(ws + 29884416);
  u16*   Wcat  = (u16*)(ws + 38273024);
  u16*   Wwb   = (u16*)(ws + 38469632);
  float* biasc = (float*)(ws + 38535168);
  float* stats = (float*)(ws + 38536704);
  float* out   = (float*)d_out;

  k0_prep<<<64, 256, 0, stream>>>(Wt, Wp, Wg, Ww, bt, bp, bg, Wcat, Wwb, biasc, stats);
  k1_proj<<<256, 256, 0, stream>>>(x, Wcat, biasc, theta, kproj, gT);
  k2_attn<<<256, 512, 0, stream>>>(theta, kproj, gT, pO, pM, pL);
  k3_wy<<<256, 256, 0, stream>>>(pO, pM, pL, Wwb, bw, wy, stats);
  k4_bn<<<2048, 256, 0, stream>>>(wy, x, stats, gamma, beta, out);
}

// Round 9
// 131.069 us; speedup vs baseline: 2.2966x; 1.0060x over previous
//
#include <hip/hip_runtime.h>
#include <cstdint>
#include <cstddef>

// NonLocalBlock3D: B=2, C=256, Ci=128, N=D*H*W=8192.
// k1 projections (+weight pack fused) -> k2 flash attention (CH=4 KV-split,
// deferred-softmax pipeline) -> k3 combine+wy GEMM+stats -> k4 BN+res.
// R3: never cap k2 VGPR via launch_bounds min-waves (spills 600 MB scratch). (512,2) safe.
// R4: 8-wave blocks can't double up (unified regs ~160+/wave); ceiling 8 waves/CU.
// R5: 128-q blocks double staging traffic -> VALU-bound. Keep 256-q blocks.
// R6: global_load_lds staging regressed (DMA serialized vs ds_read). Keep reg-staged.
// R7/R8: __builtin_amdgcn_exp2f (libm exp2f = OCML slow path); K swizzle (row&15)<<4.
//        -> 90.9us, Mfma 32 / VALU 32.
// R9: T15 deferred softmax: exp/PV of tile t-1 interleaved under QK^T(t) MFMA chain;
//     V triple-buffered (80KB LDS); S regs 2-state static-named. k0 folded into k1/k3.

typedef unsigned short u16;
typedef __bf16 bf16x8 __attribute__((ext_vector_type(8)));
typedef float f32x4 __attribute__((ext_vector_type(4)));
typedef float f32x16 __attribute__((ext_vector_type(16)));
typedef unsigned short u16x8 __attribute__((ext_vector_type(8)));

#define B_ 2
#define C_ 256
#define CI_ 128
#define N_ 8192
#define KVB 64

static __device__ __forceinline__ u16 f2bf(float f){
  unsigned u = __builtin_bit_cast(unsigned, f);
  unsigned r = (u + 0x7FFFu + ((u>>16)&1u)) >> 16;
  return (u16)r;
}
static __device__ __forceinline__ float bf2f(u16 v){
  unsigned u = ((unsigned)v) << 16;
  return __builtin_bit_cast(float, u);
}
static __device__ __forceinline__ float fexp2(float x){
  return __builtin_amdgcn_exp2f(x);     // raw v_exp_f32
}
static __device__ __forceinline__ f32x4 f4zero(){
  f32x4 v; v[0]=0.f; v[1]=0.f; v[2]=0.f; v[3]=0.f; return v;
}
static __device__ __forceinline__ f32x16 f16zero(){
  f32x16 v;
#pragma unroll
  for (int i=0;i<16;i++) v[i]=0.f;
  return v;
}
static __device__ __forceinline__ f32x4 mfma16(bf16x8 a, bf16x8 b, f32x4 c){
  return __builtin_amdgcn_mfma_f32_16x16x32_bf16(a, b, c, 0, 0, 0);
}
static __device__ __forceinline__ f32x16 mfma32(bf16x8 a, bf16x8 b, f32x16 c){
  return __builtin_amdgcn_mfma_f32_32x32x16_bf16(a, b, c, 0, 0, 0);
}
static __device__ __forceinline__ unsigned cvtpk(float lo, float hi){
  unsigned r;
  asm("v_cvt_pk_bf16_f32 %0, %1, %2" : "=v"(r) : "v"(lo), "v"(hi));
  return r;
}
static __device__ __forceinline__ void plswap(unsigned &a, unsigned &b){
  asm volatile("v_permlane32_swap_b32 %0, %1" : "+v"(a), "+v"(b));
}

#define LOG2E 1.4426950408889634f

// ---------------- K1: fused weight pack + transpose + 3 projections ----------------
__global__ __launch_bounds__(256) void k1_proj(const float* __restrict__ x,
     const float* __restrict__ Wt, const float* __restrict__ Wp,
     const float* __restrict__ Wg, const float* __restrict__ bt,
     const float* __restrict__ bp, const float* __restrict__ bg,
     u16* __restrict__ theta, u16* __restrict__ kproj, u16* __restrict__ gT,
     float* __restrict__ stats){
  __shared__ u16 At[64*264];
  __shared__ u16 Wt_[32*264];
  __shared__ u16 gbuf[32*72];
  int tid = threadIdx.x;
  int b  = blockIdx.x >> 7;
  int nb = (blockIdx.x & 127) * 64;
  int w = tid >> 6, lane = tid & 63;
  int l15 = lane & 15, kg = lane >> 4;

  if (blockIdx.x == 0){           // stats zeroing (k0 fold); k3 runs after k1 completes
    stats[tid] = 0.f; stats[256 + tid] = 0.f;
  }

  {
    int cp = tid & 127, nh = tid >> 7;
    int c0 = cp*2;
    const float* src0 = x + ((size_t)(b*C_ + c0))*N_ + nb + nh*32;
    const float* src1 = src0 + N_;
#pragma unroll
    for (int j=0;j<8;j++){
      f32x4 a = *(const f32x4*)(src0 + j*4);
      f32x4 c = *(const f32x4*)(src1 + j*4);
#pragma unroll
      for (int q=0;q<4;q++){
        unsigned pk = (unsigned)f2bf(a[q]) | ((unsigned)f2bf(c[q])<<16);
        *(unsigned*)&At[(nh*32 + j*4 + q)*264 + c0] = pk;
      }
    }
  }
  __syncthreads();

  bf16x8 afr[8];
#pragma unroll
  for (int kc=0;kc<8;kc++)
    afr[kc] = *(const bf16x8*)&At[(w*16+l15)*264 + kc*32 + kg*8];

  for (int och = 0; och < 12; och++){
    {
      int o8 = tid>>3, cp8 = tid&7;
      const float* wsel = (och<4) ? (Wt + ((size_t)(och*32 + o8))*256)
                        : (och<8) ? (Wp + ((size_t)((och-4)*32 + o8))*256)
                                  : (Wg + ((size_t)((och-8)*32 + o8))*256);
      float scl = (och<4) ? LOG2E : 1.f;
#pragma unroll
      for (int j=0;j<4;j++){
        f32x4 w0 = *(const f32x4*)(wsel + cp8*8 + j*64);
        f32x4 w1 = *(const f32x4*)(wsel + cp8*8 + j*64 + 4);
        u16 tmp[8];
#pragma unroll
        for (int q=0;q<4;q++){ tmp[q] = f2bf(w0[q]*scl); tmp[4+q] = f2bf(w1[q]*scl); }
        *(u16x8*)&Wt_[o8*264 + cp8*8 + j*64] = *(const u16x8*)tmp;
      }
    }
    __syncthreads();

    f32x4 acc0 = f4zero(), acc1 = f4zero();
#pragma unroll
    for (int kc=0;kc<8;kc++){
      bf16x8 b0 = *(const bf16x8*)&Wt_[(l15)*264 + kc*32 + kg*8];
      bf16x8 b1 = *(const bf16x8*)&Wt_[(16+l15)*264 + kc*32 + kg*8];
      acc0 = mfma16(afr[kc], b0, acc0);
      acc1 = mfma16(afr[kc], b1, acc1);
    }

    if (och < 8){
      u16* dst = (och < 4) ? theta : kproj;
      int oo = (och & 3) * 32;
#pragma unroll
      for (int of=0;of<2;of++){
        int o = oo + of*16 + l15;
        float bias = (och<4) ? bt[och*32 + of*16 + l15] * LOG2E
                             : bp[(och-4)*32 + of*16 + l15];
        f32x4 acc = of ? acc1 : acc0;
#pragma unroll
        for (int i=0;i<4;i++){
          int n = nb + w*16 + kg*4 + i;
          dst[((size_t)b*N_ + n)*CI_ + o] = f2bf(acc[i] + bias);
        }
      }
      __syncthreads();
    } else {
#pragma unroll
      for (int of=0;of<2;of++){
        int o = of*16 + l15;
        float bias = bg[(och-8)*32 + of*16 + l15];
        f32x4 acc = of ? acc1 : acc0;
#pragma unroll
        for (int i=0;i<4;i++){
          int r = w*16 + kg*4 + i;
          gbuf[o*72 + r] = f2bf(acc[i] + bias);
        }
      }
      __syncthreads();
      {
        int o = tid>>3, np = tid&7;
        int og = (och-8)*32 + o;
        u16x8 v = *(const u16x8*)&gbuf[o*72 + np*8];
        *(u16x8*)(gT + ((size_t)b*CI_ + og)*N_ + nb + np*8) = v;
      }
      __syncthreads();
    }
  }
}

// ---------------- K2: flash attention, deferred-softmax pipeline ----------------
// Grid 256 x 512 (8 waves x 32 q). bid&7 = (b,chunk) -> XCD. K dbuf 2x16K, V tbuf 3x16K.
// Iter t: QK^T(t) MFMA || exp(t-1)+cvtpk (indep) -> stage(t+1) -> PV(t-1) -> max(t) -> barrier.
__global__ __launch_bounds__(512, 2) void k2_attn(const u16* __restrict__ theta,
      const u16* __restrict__ kproj, const u16* __restrict__ gT,
      u16* __restrict__ pO, float* __restrict__ pM, float* __restrict__ pL){
  constexpr int CHUNK_N = 2048;
  constexpr int NTI = CHUNK_N / KVB;   // 32
  __shared__ char smem[81920];   // [0,32K): K dbuf, [32K,80K): V tbuf
  int tid = threadIdx.x;
  int bid = blockIdx.x;
  int combo = bid & 7;
  int b = combo & 1;
  int chunk = combo >> 1;
  int qblk = bid >> 3;
  int n0 = chunk * CHUNK_N;
  int w = tid >> 6, lane = tid & 63;
  int l31 = lane & 31, hi = lane >> 5;
  int qg = qblk*256 + w*32 + l31;

  char* kb_cur = smem;
  char* kb_nxt = smem + 16384;
  char* vb_cur = smem + 32768;
  char* vb_nxt = smem + 49152;
  char* vb_prev = smem + 65536;   // garbage at iter 0 (PV skipped)

  bf16x8 qf[8];
  {
    const u16* qsrc = theta + ((size_t)b*N_ + qg)*CI_ + hi*8;
#pragma unroll
    for (int cc=0; cc<8; cc++) qf[cc] = *(const bf16x8*)(qsrc + cc*16);
  }

  int krow_s = tid >> 3, kpart = tid & 7;
  int vrow_s = tid >> 2, vpart = tid & 3;
  const u16* ksrc = kproj + ((size_t)b*N_ + n0 + krow_s)*CI_ + kpart*16;
  const u16* vsrc = gT + ((size_t)b*CI_ + vrow_s)*N_ + n0 + vpart*16;
  int kw_off[2], vw_off[2];
#pragma unroll
  for (int j=0;j<2;j++){
    int cb = kpart*32 + j*16;
    kw_off[j] = krow_s*256 + (cb ^ ((krow_s&15)<<4));
    int kb = vpart*32 + j*16;
    vw_off[j] = vrow_s*128 + (kb ^ ((vrow_s&7)<<4));
  }
  int kswz = (l31&15)<<4;
  int vswz = (l31&7)<<4;
  int kro[8], vro[4];
#pragma unroll
  for (int cc=0;cc<8;cc++) kro[cc] = l31*256 + ((cc*32 + hi*16) ^ kswz);
#pragma unroll
  for (int ks=0;ks<4;ks++) vro[ks] = l31*128 + ((ks*32 + hi*16) ^ vswz);

  // pre-stage tile 0: K -> kb_cur, V -> vb_cur
#pragma unroll
  for (int j=0;j<2;j++){
    *(u16x8*)(kb_cur + kw_off[j]) = *(const u16x8*)(ksrc + j*8);
    *(u16x8*)(vb_cur + vw_off[j]) = *(const u16x8*)(vsrc + j*8);
  }
  __syncthreads();

  f32x16 oacc[4];
#pragma unroll
  for (int i=0;i<4;i++) oacc[i] = f16zero();
  float mrun = -1e30f, lrun = 0.f;
  f32x16 sA0, sB0, sA1, sB1;

#define K2_ROT() { char* _t = vb_prev; vb_prev = vb_cur; vb_cur = vb_nxt; vb_nxt = _t; \
                   char* _k = kb_cur; kb_cur = kb_nxt; kb_nxt = _k; }

#define K2_MAX(CA, CB) { float t8[8]; \
    _Pragma("unroll") \
    for (int i=0;i<8;i++) t8[i] = fmaxf(fmaxf(CA[i], CA[i+8]), fmaxf(CB[i], CB[i+8])); \
    float mx = fmaxf(fmaxf(fmaxf(t8[0],t8[4]),fmaxf(t8[1],t8[5])), \
                     fmaxf(fmaxf(t8[2],t8[6]),fmaxf(t8[3],t8[7]))); \
    mx = fmaxf(mx, __shfl_xor(mx, 32)); \
    if (__any(mx > mrun + 12.f)){ \
      float mnew = fmaxf(mrun, mx); \
      float sc = fexp2(mrun - mnew); \
      lrun *= sc; \
      _Pragma("unroll") \
      for (int i=0;i<4;i++){ _Pragma("unroll") for (int r=0;r<16;r++) oacc[i][r] *= sc; } \
      mrun = mnew; } }

#define K2_EXP(PA, PB, pA, pB) \
    float pA[16], pB[16]; \
    _Pragma("unroll") \
    for (int r=0;r<16;r++){ pA[r] = fexp2(PA[r]-mrun); pB[r] = fexp2(PB[r]-mrun); } \
    { float s8[8]; \
      _Pragma("unroll") \
      for (int i=0;i<8;i++) s8[i] = (pA[i]+pA[i+8]) + (pB[i]+pB[i+8]); \
      float ps = ((s8[0]+s8[4])+(s8[1]+s8[5])) + ((s8[2]+s8[6])+(s8[3]+s8[7])); \
      ps += __shfl_xor(ps, 32); lrun += ps; }

#define K2_PV(pA, pB) \
    __builtin_amdgcn_s_setprio(1); \
    _Pragma("unroll") \
    for (int ks=0; ks<4; ks++){ \
      const float* P = (ks<2) ? pA : pB; \
      int r0 = (ks&1)*8; \
      unsigned a0 = cvtpk(P[r0+0], P[r0+1]); \
      unsigned b0 = cvtpk(P[r0+4], P[r0+5]); \
      unsigned a1 = cvtpk(P[r0+2], P[r0+3]); \
      unsigned b1 = cvtpk(P[r0+6], P[r0+7]); \
      plswap(a0, b0); plswap(a1, b1); \
      union { unsigned u[4]; bf16x8 v; } pb; \
      pb.u[0]=a0; pb.u[1]=a1; pb.u[2]=b0; pb.u[3]=b1; \
      _Pragma("unroll") \
      for (int c2=0; c2<4; c2++){ \
        bf16x8 vf = *(const bf16x8*)(vb_prev + c2*4096 + vro[ks]); \
        oacc[c2] = mfma32(vf, pb.v, oacc[c2]); \
      } \
    } \
    __builtin_amdgcn_s_setprio(0);

#define K2_QKT(CA, CB) \
    CA = f16zero(); CB = f16zero(); \
    __builtin_amdgcn_s_setprio(1); \
    _Pragma("unroll") \
    for (int cc=0; cc<8; cc++){ \
      bf16x8 kf0 = *(const bf16x8*)(kb_cur + kro[cc]); \
      bf16x8 kf1 = *(const bf16x8*)(kb_cur + 8192 + kro[cc]); \
      CA = mfma32(kf0, qf[cc], CA); \
      CB = mfma32(kf1, qf[cc], CB); \
    } \
    __builtin_amdgcn_s_setprio(0);

#define K2_LOADS(T) \
    int tn = ((T)+1 < NTI) ? ((T)+1) : (NTI-1); \
    u16x8 kst0 = *(const u16x8*)(ksrc + (size_t)tn*KVB*CI_); \
    u16x8 kst1 = *(const u16x8*)(ksrc + (size_t)tn*KVB*CI_ + 8); \
    u16x8 vst0 = *(const u16x8*)(vsrc + tn*KVB); \
    u16x8 vst1 = *(const u16x8*)(vsrc + tn*KVB + 8);

#define K2_WRITES() \
    *(u16x8*)(kb_nxt + kw_off[0]) = kst0; *(u16x8*)(kb_nxt + kw_off[1]) = kst1; \
    *(u16x8*)(vb_nxt + vw_off[0]) = vst0; *(u16x8*)(vb_nxt + vw_off[1]) = vst1;

#define K2_ITER(T, CA, CB, PA, PB) { \
    K2_LOADS(T) \
    K2_QKT(CA, CB) \
    K2_EXP(PA, PB, pA_, pB_) \
    K2_WRITES() \
    K2_PV(pA_, pB_) \
    K2_MAX(CA, CB) \
    __syncthreads(); \
    K2_ROT() }

  // iter 0 (no prev): QK^T(0), stage(1), max(0)
  {
    K2_LOADS(0)
    K2_QKT(sA0, sB0)
    K2_WRITES()
    K2_MAX(sA0, sB0)
    __syncthreads();
    K2_ROT()
  }
  // iters 1..30 in pairs, then 31
  for (int t = 1; t < NTI-1; t += 2){
    K2_ITER(t,   sA1, sB1, sA0, sB0)
    K2_ITER(t+1, sA0, sB0, sA1, sB1)
  }
  K2_ITER(NTI-1, sA1, sB1, sA0, sB0)

  // tail: exp + PV for tile NTI-1 (prev = sA1/sB1; V in vb_prev after last rotate)
  {
    K2_EXP(sA1, sB1, pA_, pB_)
    K2_PV(pA_, pB_)
  }
  __syncthreads();   // PV reads of vb done before O-region writes below

  // epilogue: O^T -> per-wave LDS region (bf16, swizzled) -> coalesced partial store
  char* region = smem + w*8192;
#pragma unroll
  for (int c2=0;c2<4;c2++)
#pragma unroll
    for (int r=0;r<16;r++){
      int c = c2*32 + (r&3) + 8*(r>>2) + 4*hi;
      *(u16*)(region + l31*256 + ((c*2) ^ vswz)) = f2bf(oacc[c2][r]);
    }
  __syncthreads();
  {
    int ql = lane >> 1, half = lane & 1;
    int qg2 = qblk*256 + w*32 + ql;
    u16* dst = pO + ((size_t)(chunk*2 + b)*N_ + qg2)*CI_ + half*64;
    int rswz = (ql&7)<<4;
#pragma unroll
    for (int j=0;j<8;j++){
      u16x8 v2 = *(const u16x8*)(region + ql*256 + ((half*128 + j*16) ^ rswz));
      *(u16x8*)(dst + j*8) = v2;
    }
  }
  if (hi == 0){
    pM[(size_t)(chunk*2 + b)*N_ + qg] = mrun;
    pL[(size_t)(chunk*2 + b)*N_ + qg] = lrun;
  }
}

// ---------------- K3: fused combine(pO chunks) + wy = Ww @ y + bw + stats ----------------
__global__ __launch_bounds__(256) void k3_wy(const u16* __restrict__ pO,
    const float* __restrict__ pM, const float* __restrict__ pL,
    const float* __restrict__ Ww, const float* __restrict__ bw,
    u16* __restrict__ wy, float* __restrict__ stats){
  __shared__ u16 Yt[64*136];
  __shared__ u16 Wt_[64*136];
  __shared__ float wyb[64*72];
  int tid = threadIdx.x;
  int b  = blockIdx.x >> 7;
  int nb = (blockIdx.x & 127) * 64;
  int w = tid>>6, lane = tid&63;
  int l15 = lane&15, kg = lane>>4;

  // stage y tile [64 n][128 c]: combine 4 KV-chunk partials -> bf16
  {
    int n = tid>>2, cp = tid&3;
    size_t q = (size_t)nb + n;
    float m[4], l[4];
#pragma unroll
    for (int ch=0; ch<4; ch++){
      m[ch] = pM[(size_t)(ch*2+b)*N_ + q];
      l[ch] = pL[(size_t)(ch*2+b)*N_ + q];
    }
    float M = fmaxf(fmaxf(m[0],m[1]), fmaxf(m[2],m[3]));
    float wts[4]; float L = 0.f;
#pragma unroll
    for (int ch=0; ch<4; ch++){ wts[ch] = exp2f(m[ch]-M); L += wts[ch]*l[ch]; }
    float inv = 1.f/L;
#pragma unroll
    for (int j=0;j<4;j++){
      int c0 = cp*32 + j*8;
      float acc[8];
#pragma unroll
      for (int i=0;i<8;i++) acc[i]=0.f;
#pragma unroll
      for (int ch=0; ch<4; ch++){
        u16x8 v = *(const u16x8*)(pO + ((size_t)(ch*2+b)*N_ + q)*CI_ + c0);
#pragma unroll
        for (int i=0;i<8;i++) acc[i] += wts[ch]*bf2f(v[i]);
      }
#pragma unroll
      for (int i=0;i<4;i++){
        unsigned pk = (unsigned)f2bf(acc[2*i]*inv) | ((unsigned)f2bf(acc[2*i+1]*inv)<<16);
        *(unsigned*)&Yt[n*136 + c0 + 2*i] = pk;
      }
    }
  }
  __syncthreads();

  bf16x8 afr[4];
#pragma unroll
  for (int kc=0;kc<4;kc++)
    afr[kc] = *(const bf16x8*)&Yt[(w*16+l15)*136 + kc*32 + kg*8];

  for (int oc=0; oc<4; oc++){
    {
      int o = tid>>2, cp = tid&3;
      const float* src = Ww + ((size_t)(oc*64 + o))*CI_ + cp*32;
#pragma unroll
      for (int j=0;j<4;j++){
        f32x4 w0 = *(const f32x4*)(src + j*8);
        f32x4 w1 = *(const f32x4*)(src + j*8 + 4);
        u16 tmp[8];
#pragma unroll
        for (int q2=0;q2<4;q2++){ tmp[q2] = f2bf(w0[q2]); tmp[4+q2] = f2bf(w1[q2]); }
        *(u16x8*)&Wt_[o*136 + cp*32 + j*8] = *(const u16x8*)tmp;
      }
    }
    __syncthreads();

    f32x4 acc[4];
#pragma unroll
    for (int of=0;of<4;of++) acc[of] = f4zero();
#pragma unroll
    for (int kc=0;kc<4;kc++){
#pragma unroll
      for (int of=0;of<4;of++){
        bf16x8 bfr = *(const bf16x8*)&Wt_[(of*16+l15)*136 + kc*32 + kg*8];
        acc[of] = mfma16(afr[kc], bfr, acc[of]);
      }
    }
#pragma unroll
    for (int of=0;of<4;of++){
#pragma unroll
      for (int i=0;i<4;i++)
        wyb[(of*16+l15)*72 + w*16 + kg*4 + i] = acc[of][i];
    }
    __syncthreads();
    {
      int o = tid>>2, np = tid&3;
      int og = oc*64 + o;
      float bias = bw[og];
      float sm = 0.f, sq = 0.f;
      u16* dst = wy + ((size_t)b*C_ + og)*N_ + nb + np*16;
      u16 buf[16];
#pragma unroll
      for (int j=0;j<4;j++){
#pragma unroll
        for (int q2=0;q2<4;q2++){
          float t2 = wyb[o*72 + np*16 + j*4 + q2] + bias;
          buf[j*4+q2] = f2bf(t2); sm += t2; sq += t2*t2;
        }
      }
      *(u16x8*)dst = *(const u16x8*)&buf[0];
      *(u16x8*)(dst+8) = *(const u16x8*)&buf[8];
      sm += __shfl_xor(sm, 1); sm += __shfl_xor(sm, 2);
      sq += __shfl_xor(sq, 1); sq += __shfl_xor(sq, 2);
      if ((tid&3)==0){
        atomicAdd(&stats[og], sm);
        atomicAdd(&stats[256+og], sq);
      }
    }
    __syncthreads();
  }
}

// ---------------- K4: BN (batch stats) + residual ----------------
__global__ __launch_bounds__(256) void k4_bn(const u16* __restrict__ wy,
    const float* __restrict__ x, const float* __restrict__ stats,
    const float* __restrict__ gamma, const float* __restrict__ beta,
    float* __restrict__ out){
  size_t base = ((size_t)blockIdx.x)*2048 + (size_t)threadIdx.x*8;
  int o = (int)((base >> 13) & 255);
  const float invn = 1.f/16384.f;
  float mean = stats[o]*invn;
  float var  = stats[256+o]*invn - mean*mean;
  float rs = rsqrtf(var + 1e-5f);
  float g = gamma[o]*rs;
  float bb = beta[o];
  u16x8 a = *(const u16x8*)(wy + base);
  f32x4 x0 = *(const f32x4*)(x + base);
  f32x4 x1 = *(const f32x4*)(x + base + 4);
  f32x4 r0, r1;
#pragma unroll
  for (int q=0;q<4;q++){
    r0[q] = (bf2f(a[q])-mean)*g + bb + x0[q];
    r1[q] = (bf2f(a[4+q])-mean)*g + bb + x1[q];
  }
  *(f32x4*)(out + base)     = r0;
  *(f32x4*)(out + base + 4) = r1;
}

extern "C" void kernel_launch(void* const* d_in, const int* in_sizes, int n_in,
                              void* d_out, int out_size, void* d_ws, size_t ws_size,
                              hipStream_t stream){
  const float* x     = (const float*)d_in[0];
  const float* Wt    = (const float*)d_in[1];
  const float* bt    = (const float*)d_in[2];
  const float* Wp    = (const float*)d_in[3];
  const float* bp    = (const float*)d_in[4];
  const float* Wg    = (const float*)d_in[5];
  const float* bg    = (const float*)d_in[6];
  const float* Ww    = (const float*)d_in[7];
  const float* bw    = (const float*)d_in[8];
  const float* gamma = (const float*)d_in[9];
  const float* beta  = (const float*)d_in[10];

  char* ws = (char*)d_ws;
  // [0,4M) theta | [4M,8M) kproj | [8M,12M) gT (bf16)
  // [12M,+16M) pO bf16 [4ch][2b][8192][128] | pM 256K | pL 256K | wy bf16 8M | stats 2K
  u16*   theta = (u16*)(ws + 0);
  u16*   kproj = (u16*)(ws + 4194304);
  u16*   gT    = (u16*)(ws + 8388608);
  u16*   pO    = (u16*)(ws + 12582912);
  float* pM    = (float*)(ws + 29360128);
  float* pL    = (float*)(ws + 29622272);
  u16*   wy    = (u16*)(ws + 29884416);
  float* stats = (float*)(ws + 38273024);
  float* out   = (float*)d_out;

  k1_proj<<<256, 256, 0, stream>>>(x, Wt, Wp, Wg, bt, bp, bg, theta, kproj, gT, stats);
  k2_attn<<<256, 512, 0, stream>>>(theta, kproj, gT, pO, pM, pL);
  k3_wy<<<256, 256, 0, stream>>>(pO, pM, pL, Ww, bw, wy, stats);
  k4_bn<<<2048, 256, 0, stream>>>(wy, x, stats, gamma, beta, out);
}